// Round 1
// baseline (3649.855 us; speedup 1.0000x reference)
//
#include <hip/hip_runtime.h>
#include <math.h>

#define S_LEN 2048
#define E_DIM 1024
#define INNERD 2048
#define NHEAD 4
#define DHEAD 512
#define BATCH 2

__device__ __forceinline__ float swishf(float x) { return x / (1.0f + expf(-x)); }
__device__ __forceinline__ float logsigf(float x) {
  return (x >= 0.0f) ? -log1pf(expf(-x)) : (x - log1pf(expf(x)));
}

// ---------------- fp32 GEMM: C[M,N] = A[M,K] * B[K,N], 64x64 tile, BK=16 ----------
__global__ __launch_bounds__(256) void gemm_f32(const float* __restrict__ A,
                                                const float* __restrict__ B,
                                                float* __restrict__ C,
                                                int M, int N, int K) {
  __shared__ float As[16][68];
  __shared__ float Bs[16][68];
  const int tid = threadIdx.x;
  const int row0 = blockIdx.y * 64, col0 = blockIdx.x * 64;
  const int tx = tid & 15, ty = tid >> 4;
  float acc[4][4];
#pragma unroll
  for (int i = 0; i < 4; ++i)
#pragma unroll
    for (int j = 0; j < 4; ++j) acc[i][j] = 0.0f;

  for (int k0 = 0; k0 < K; k0 += 16) {
    {
      const int r = tid >> 2, kk = (tid & 3) << 2;
      const float4 av = *(const float4*)(A + (size_t)(row0 + r) * K + k0 + kk);
      As[kk + 0][r] = av.x; As[kk + 1][r] = av.y;
      As[kk + 2][r] = av.z; As[kk + 3][r] = av.w;
    }
    {
      const int kk = tid >> 4, c = (tid & 15) << 2;
      *(float4*)(&Bs[kk][c]) = *(const float4*)(B + (size_t)(k0 + kk) * N + col0 + c);
    }
    __syncthreads();
#pragma unroll
    for (int kk = 0; kk < 16; ++kk) {
      const float4 a4 = *(const float4*)(&As[kk][ty << 2]);
      const float4 b4 = *(const float4*)(&Bs[kk][tx << 2]);
      const float av[4] = {a4.x, a4.y, a4.z, a4.w};
      const float bv[4] = {b4.x, b4.y, b4.z, b4.w};
#pragma unroll
      for (int i = 0; i < 4; ++i)
#pragma unroll
        for (int j = 0; j < 4; ++j) acc[i][j] += av[i] * bv[j];
    }
    __syncthreads();
  }
#pragma unroll
  for (int i = 0; i < 4; ++i) {
    *(float4*)(C + (size_t)(row0 + (ty << 2) + i) * N + col0 + (tx << 2)) =
        make_float4(acc[i][0], acc[i][1], acc[i][2], acc[i][3]);
  }
}

// ---------------- causal depthwise conv (K=4) + swish ----------------
__global__ __launch_bounds__(256) void conv_swish_kernel(const float* __restrict__ xinner,
                                                         const float* __restrict__ cw,
                                                         const float* __restrict__ cb,
                                                         float* __restrict__ xact) {
  const int idx = blockIdx.x * 256 + threadIdx.x;  // < B*S*INNER
  const int c = idx & (INNERD - 1);
  const int s = (idx >> 11) & (S_LEN - 1);
  const int b = idx >> 22;
  float accv = cb[c];
#pragma unroll
  for (int i = 0; i < 4; ++i) {
    const int sj = s - 3 + i;
    if (sj >= 0)
      accv += xinner[((size_t)(b * S_LEN + sj)) * (2 * INNERD) + c] * cw[i * INNERD + c];
  }
  xact[idx] = swishf(accv);
}

// ------- headwise 4x4 projections (q,k,v) + ig/fg gate preactivations -------
__global__ __launch_bounds__(256) void headwise_kernel(
    const float* __restrict__ xact, const float* __restrict__ xinner,
    const float* __restrict__ Wq, const float* __restrict__ Wk, const float* __restrict__ Wv,
    const float* __restrict__ Wig, const float* __restrict__ big,
    const float* __restrict__ Wfg, const float* __restrict__ bfg,
    float* __restrict__ q, float* __restrict__ k, float* __restrict__ v,
    float* __restrict__ igpre, float* __restrict__ fgpre) {
  __shared__ float red[8][264];
  const int bs = blockIdx.x;
  const int t = threadIdx.x;
  const size_t ro2 = (size_t)bs * INNERD;
  const size_t ro4 = (size_t)bs * (2 * INNERD);
  float iga[4] = {0, 0, 0, 0}, fga[4] = {0, 0, 0, 0};
#pragma unroll
  for (int hh = 0; hh < 2; ++hh) {
    const int h = t * 2 + hh;
    const float4 xa = *(const float4*)(xact + ro2 + h * 4);
    const float4 xm = *(const float4*)(xinner + ro4 + h * 4);
    float qv[4], kv[4], vv[4];
#pragma unroll
    for (int o = 0; o < 4; ++o) {
      const float4 wq = *(const float4*)(Wq + (size_t)(h * 4 + o) * 4);
      const float4 wk = *(const float4*)(Wk + (size_t)(h * 4 + o) * 4);
      const float4 wv = *(const float4*)(Wv + (size_t)(h * 4 + o) * 4);
      qv[o] = wq.x * xa.x + wq.y * xa.y + wq.z * xa.z + wq.w * xa.w;
      kv[o] = wk.x * xa.x + wk.y * xa.y + wk.z * xa.z + wk.w * xa.w;
      vv[o] = wv.x * xm.x + wv.y * xm.y + wv.z * xm.z + wv.w * xm.w;
    }
    *(float4*)(q + ro2 + h * 4) = make_float4(qv[0], qv[1], qv[2], qv[3]);
    *(float4*)(k + ro2 + h * 4) = make_float4(kv[0], kv[1], kv[2], kv[3]);
    *(float4*)(v + ro2 + h * 4) = make_float4(vv[0], vv[1], vv[2], vv[3]);
#pragma unroll
    for (int o = 0; o < 4; ++o) {
      const int j0 = h * 4 + o;
      const float4 wi0 = *(const float4*)(Wig + (size_t)j0 * 4);
      const float4 wi1 = *(const float4*)(Wig + (size_t)(INNERD + j0) * 4);
      const float4 wi2 = *(const float4*)(Wig + (size_t)(2 * INNERD + j0) * 4);
      iga[0] += qv[o] * wi0.x + kv[o] * wi1.x + vv[o] * wi2.x;
      iga[1] += qv[o] * wi0.y + kv[o] * wi1.y + vv[o] * wi2.y;
      iga[2] += qv[o] * wi0.z + kv[o] * wi1.z + vv[o] * wi2.z;
      iga[3] += qv[o] * wi0.w + kv[o] * wi1.w + vv[o] * wi2.w;
      const float4 wf0 = *(const float4*)(Wfg + (size_t)j0 * 4);
      const float4 wf1 = *(const float4*)(Wfg + (size_t)(INNERD + j0) * 4);
      const float4 wf2 = *(const float4*)(Wfg + (size_t)(2 * INNERD + j0) * 4);
      fga[0] += qv[o] * wf0.x + kv[o] * wf1.x + vv[o] * wf2.x;
      fga[1] += qv[o] * wf0.y + kv[o] * wf1.y + vv[o] * wf2.y;
      fga[2] += qv[o] * wf0.z + kv[o] * wf1.z + vv[o] * wf2.z;
      fga[3] += qv[o] * wf0.w + kv[o] * wf1.w + vv[o] * wf2.w;
    }
  }
#pragma unroll
  for (int g = 0; g < 4; ++g) { red[g][t] = iga[g]; red[g + 4][t] = fga[g]; }
  __syncthreads();
  for (int off = 128; off >= 1; off >>= 1) {
    if (t < off) {
#pragma unroll
      for (int g = 0; g < 8; ++g) red[g][t] += red[g][t + off];
    }
    __syncthreads();
  }
  if (t < 4) {
    const int b = bs >> 11, s2 = bs & (S_LEN - 1);
    igpre[((size_t)(b * NHEAD + t)) * S_LEN + s2] = red[t][0] + big[t];
  } else if (t < 8) {
    const int b = bs >> 11, s2 = bs & (S_LEN - 1);
    fgpre[((size_t)(b * NHEAD + (t - 4))) * S_LEN + s2] = red[t][0] + bfg[t - 4];
  }
}

// -------- per-(b,n) scan: L=cumsum(logsig(fg)), a=ig-L, rm=runmax(a), e=exp(-(L+rm))
__global__ __launch_bounds__(256) void scan_kernel(const float* __restrict__ igpre,
                                                   const float* __restrict__ fgpre,
                                                   float* __restrict__ a_o,
                                                   float* __restrict__ rm_o,
                                                   float* __restrict__ e_o) {
  __shared__ float sd[256];
  const int bn = blockIdx.x, t = threadIdx.x;
  const size_t base = (size_t)bn * S_LEN + t * 8;
  float cs[8];
  float run = 0.0f;
#pragma unroll
  for (int u = 0; u < 8; ++u) {
    run += logsigf(fgpre[base + u]);
    cs[u] = run;
  }
  sd[t] = run;
  __syncthreads();
  for (int off = 1; off < 256; off <<= 1) {
    const float vv2 = (t >= off) ? sd[t - off] : 0.0f;
    __syncthreads();
    sd[t] += vv2;
    __syncthreads();
  }
  const float exs = (t > 0) ? sd[t - 1] : 0.0f;
  __syncthreads();
  float av[8], pm[8];
  float rmax = -INFINITY;
#pragma unroll
  for (int u = 0; u < 8; ++u) {
    const float L = exs + cs[u];
    cs[u] = L;  // cs now holds L
    av[u] = igpre[base + u] - L;
    rmax = fmaxf(rmax, av[u]);
    pm[u] = rmax;
  }
  sd[t] = rmax;
  __syncthreads();
  for (int off = 1; off < 256; off <<= 1) {
    const float vv2 = (t >= off) ? sd[t - off] : -INFINITY;
    __syncthreads();
    sd[t] = fmaxf(sd[t], vv2);
    __syncthreads();
  }
  const float exm = (t > 0) ? sd[t - 1] : -INFINITY;
#pragma unroll
  for (int u = 0; u < 8; ++u) {
    const float rmv = fmaxf(exm, pm[u]);
    a_o[base + u] = av[u];
    rm_o[base + u] = rmv;
    e_o[base + u] = expf(-(cs[u] + rmv));
  }
}

// ---------------- mLSTM core: causal D-weighted attention, BQ=16, TJ=64 ----------
__global__ __launch_bounds__(256) void mlstm_kernel(
    const float* __restrict__ qg, const float* __restrict__ kg, const float* __restrict__ vg,
    const float* __restrict__ ag, const float* __restrict__ rmg, const float* __restrict__ eg,
    float* __restrict__ hg) {
  __shared__ float qs[16][516];
  __shared__ float ks[64][132];
  __shared__ float stile[16][68];
  __shared__ float a_s[64];
  __shared__ float rm_s[16];
  __shared__ float inorm_s[16];

  const int tid = threadIdx.x;
  const int bn = blockIdx.y;
  const int b = bn >> 2, n = bn & 3;
  const int i0 = blockIdx.x << 4;
  const size_t rowbase = ((size_t)b * S_LEN) * (size_t)INNERD + (size_t)n * DHEAD;

  // load Q tile 16 x 512
#pragma unroll
  for (int u = 0; u < 8; ++u) {
    const int idx = u * 1024 + tid * 4;
    const int r = idx >> 9, c = idx & 511;
    *(float4*)(&qs[r][c]) = *(const float4*)(qg + rowbase + (size_t)(i0 + r) * INNERD + c);
  }
  if (tid < 16) rm_s[tid] = rmg[(size_t)bn * S_LEN + i0 + tid];

  const int si = tid >> 4, sj0 = (tid & 15) << 2;
  const int ri = tid >> 4, cg = tid & 15;
  float acc[32];
#pragma unroll
  for (int u = 0; u < 32; ++u) acc[u] = 0.0f;
  float rs = 0.0f;

  const int numtiles = ((i0 + 15) >> 6) + 1;
  for (int jt = 0; jt < numtiles; ++jt) {
    const int j0g = jt << 6;
    if (tid < 64) a_s[tid] = ag[(size_t)bn * S_LEN + j0g + tid];
    float sacc[4] = {0, 0, 0, 0};
#pragma unroll
    for (int ch = 0; ch < 4; ++ch) {
      // load K chunk 64 x 128
#pragma unroll
      for (int u = 0; u < 8; ++u) {
        const int idx = u * 1024 + tid * 4;
        const int r = idx >> 7, c = idx & 127;
        *(float4*)(&ks[r][c]) =
            *(const float4*)(kg + rowbase + (size_t)(j0g + r) * INNERD + (ch << 7) + c);
      }
      __syncthreads();
#pragma unroll 8
      for (int kk = 0; kk < 128; kk += 4) {
        const float4 q4 = *(const float4*)(&qs[si][(ch << 7) + kk]);
#pragma unroll
        for (int jj = 0; jj < 4; ++jj) {
          const float4 k4 = *(const float4*)(&ks[sj0 + jj][kk]);
          sacc[jj] += q4.x * k4.x + q4.y * k4.y + q4.z * k4.z + q4.w * k4.w;
        }
      }
      __syncthreads();
    }
    // gating + causal mask -> stile
    {
      const int igl = i0 + si;
      const float rmv = rm_s[si];
#pragma unroll
      for (int jj = 0; jj < 4; ++jj) {
        const int jg = j0g + sj0 + jj;
        float cval = 0.0f;
        if (jg <= igl)
          cval = sacc[jj] * 0.044194173824159216f * expf(a_s[sj0 + jj] - rmv);
        stile[si][sj0 + jj] = cval;
      }
    }
    __syncthreads();
    if (tid < 16) {
      float r2 = 0.0f;
#pragma unroll
      for (int j = 0; j < 64; ++j) r2 += stile[tid][j];
      rs += r2;
    }
    // PV accumulate
#pragma unroll
    for (int ch = 0; ch < 4; ++ch) {
#pragma unroll
      for (int u = 0; u < 8; ++u) {
        const int idx = u * 1024 + tid * 4;
        const int r = idx >> 7, c = idx & 127;
        *(float4*)(&ks[r][c]) =
            *(const float4*)(vg + rowbase + (size_t)(j0g + r) * INNERD + (ch << 7) + c);
      }
      __syncthreads();
#pragma unroll 8
      for (int j = 0; j < 64; ++j) {
        const float cf = stile[ri][j];
        const float4 v0 = *(const float4*)(&ks[j][cg * 8]);
        const float4 v1 = *(const float4*)(&ks[j][cg * 8 + 4]);
        acc[ch * 8 + 0] += cf * v0.x; acc[ch * 8 + 1] += cf * v0.y;
        acc[ch * 8 + 2] += cf * v0.z; acc[ch * 8 + 3] += cf * v0.w;
        acc[ch * 8 + 4] += cf * v1.x; acc[ch * 8 + 5] += cf * v1.y;
        acc[ch * 8 + 6] += cf * v1.z; acc[ch * 8 + 7] += cf * v1.w;
      }
      __syncthreads();
    }
  }
  if (tid < 16) {
    const float ev = eg[(size_t)bn * S_LEN + i0 + tid];
    inorm_s[tid] = 1.0f / (fmaxf(fabsf(rs), ev) + 1e-6f);
  }
  __syncthreads();
  const float sc = inorm_s[ri];
#pragma unroll
  for (int ch = 0; ch < 4; ++ch) {
    float* dst = hg + rowbase + (size_t)(i0 + ri) * INNERD + (ch << 7) + cg * 8;
    *(float4*)dst = make_float4(acc[ch * 8 + 0] * sc, acc[ch * 8 + 1] * sc,
                                acc[ch * 8 + 2] * sc, acc[ch * 8 + 3] * sc);
    *(float4*)(dst + 4) = make_float4(acc[ch * 8 + 4] * sc, acc[ch * 8 + 5] * sc,
                                      acc[ch * 8 + 6] * sc, acc[ch * 8 + 7] * sc);
  }
}

// ------- multi-head LN over DH + skip from conv-act + swish(z) gate -------
__global__ __launch_bounds__(256) void mhln_kernel(const float* __restrict__ h,
                                                   const float* __restrict__ xact,
                                                   const float* __restrict__ xinner,
                                                   const float* __restrict__ normw,
                                                   const float* __restrict__ skip,
                                                   float* __restrict__ hstate) {
  const int bs = blockIdx.x, t = threadIdx.x;
  const int n = t >> 6, lane = t & 63;
  const size_t hb = (size_t)bs * INNERD + n * DHEAD + lane * 8;
  const float4 v0 = *(const float4*)(h + hb);
  const float4 v1 = *(const float4*)(h + hb + 4);
  float vals[8] = {v0.x, v0.y, v0.z, v0.w, v1.x, v1.y, v1.z, v1.w};
  float sum = 0.0f;
#pragma unroll
  for (int u = 0; u < 8; ++u) sum += vals[u];
#pragma unroll
  for (int m = 32; m >= 1; m >>= 1) sum += __shfl_xor(sum, m, 64);
  const float mu = sum * (1.0f / 512.0f);
  float vs2 = 0.0f;
#pragma unroll
  for (int u = 0; u < 8; ++u) { const float d = vals[u] - mu; vs2 += d * d; }
#pragma unroll
  for (int m = 32; m >= 1; m >>= 1) vs2 += __shfl_xor(vs2, m, 64);
  const float rstd = rsqrtf(vs2 * (1.0f / 512.0f) + 1e-6f);
  float out[8];
#pragma unroll
  for (int u = 0; u < 8; ++u) {
    const int cp = n * DHEAD + lane * 8 + u;
    const float hn = (vals[u] - mu) * rstd * normw[cp];
    const float z = xinner[(size_t)bs * (2 * INNERD) + INNERD + cp];
    out[u] = (hn + skip[cp] * xact[(size_t)bs * INNERD + cp]) * swishf(z);
  }
  *(float4*)(hstate + hb) = make_float4(out[0], out[1], out[2], out[3]);
  *(float4*)(hstate + hb + 4) = make_float4(out[4], out[5], out[6], out[7]);
}

extern "C" void kernel_launch(void* const* d_in, const int* in_sizes, int n_in,
                              void* d_out, int out_size, void* d_ws, size_t ws_size,
                              hipStream_t stream) {
  const float* x     = (const float*)d_in[0];
  const float* Wup   = (const float*)d_in[1];
  const float* cw    = (const float*)d_in[2];
  const float* cb    = (const float*)d_in[3];
  const float* Wq    = (const float*)d_in[4];
  const float* Wk    = (const float*)d_in[5];
  const float* Wv    = (const float*)d_in[6];
  const float* Wig   = (const float*)d_in[7];
  const float* big   = (const float*)d_in[8];
  const float* Wfg   = (const float*)d_in[9];
  const float* bfg   = (const float*)d_in[10];
  const float* normw = (const float*)d_in[11];
  const float* skip  = (const float*)d_in[12];
  const float* Wdown = (const float*)d_in[13];
  float* out = (float*)d_out;

  float* ws = (float*)d_ws;
  size_t off = 0;
  const size_t MROWS = (size_t)BATCH * S_LEN;          // 4096
  float* xinner = ws + off; off += MROWS * (2 * INNERD);  // 16.7M
  float* xact   = ws + off; off += MROWS * INNERD;
  float* q      = ws + off; off += MROWS * INNERD;
  float* k      = ws + off; off += MROWS * INNERD;
  float* v      = ws + off; off += MROWS * INNERD;
  float* h      = ws + off; off += MROWS * INNERD;
  float* igpre  = ws + off; off += (size_t)BATCH * NHEAD * S_LEN;
  float* fgpre  = ws + off; off += (size_t)BATCH * NHEAD * S_LEN;
  float* a_buf  = ws + off; off += (size_t)BATCH * NHEAD * S_LEN;
  float* rm_buf = ws + off; off += (size_t)BATCH * NHEAD * S_LEN;
  float* e_buf  = ws + off; off += (size_t)BATCH * NHEAD * S_LEN;
  if (ws_size < off * sizeof(float)) return;  // fail loudly via wrong output
  float* hstate = k;  // k unused after mlstm_kernel -> reuse

  gemm_f32<<<dim3(64, 64), 256, 0, stream>>>(x, Wup, xinner, 4096, 4096, 1024);
  conv_swish_kernel<<<32768, 256, 0, stream>>>(xinner, cw, cb, xact);
  headwise_kernel<<<4096, 256, 0, stream>>>(xact, xinner, Wq, Wk, Wv, Wig, big, Wfg,
                                            bfg, q, k, v, igpre, fgpre);
  scan_kernel<<<8, 256, 0, stream>>>(igpre, fgpre, a_buf, rm_buf, e_buf);
  mlstm_kernel<<<dim3(128, 8), 256, 0, stream>>>(q, k, v, a_buf, rm_buf, e_buf, h);
  mhln_kernel<<<4096, 256, 0, stream>>>(h, xact, xinner, normw, skip, hstate);
  gemm_f32<<<dim3(16, 64), 256, 0, stream>>>(hstate, Wdown, out, 4096, 1024, 2048);
}

// Round 2
// 595.175 us; speedup vs baseline: 6.1324x; 6.1324x over previous
//
#include <hip/hip_runtime.h>
#include <math.h>

#define S_LEN 2048
#define INNERD 2048
#define NHEAD 4
#define DHEAD 512
#define BATCH 2
#define SCALE_QK 0.044194173824159216f

typedef __attribute__((ext_vector_type(8))) short short8v;
typedef __attribute__((ext_vector_type(4))) float f32x4;

#define MFMA_BF16(A, B, C) __builtin_amdgcn_mfma_f32_16x16x32_bf16(A, B, C, 0, 0, 0)

__device__ __forceinline__ void gll16(const void* g, void* l) {
  __builtin_amdgcn_global_load_lds((const __attribute__((address_space(1))) unsigned int*)g,
                                   (__attribute__((address_space(3))) unsigned int*)l,
                                   16, 0, 0);
}

__device__ __forceinline__ unsigned short f2bf(float x) {
  union { float f; unsigned u; } v; v.f = x;
  unsigned r = v.u + 0x7FFFu + ((v.u >> 16) & 1u);
  return (unsigned short)(r >> 16);
}
__device__ __forceinline__ float bf2f(unsigned short x) {
  union { unsigned u; float f; } v; v.u = ((unsigned)x) << 16; return v.f;
}
__device__ __forceinline__ float swishf(float x) { return x / (1.0f + __expf(-x)); }
__device__ __forceinline__ float logsigf(float x) {
  return (x >= 0.0f) ? -log1pf(expf(-x)) : (x - log1pf(expf(x)));
}

// ---------------- cast f32 -> bf16 (8 elems/thread) ----------------
__global__ __launch_bounds__(256) void cast_kernel(const float* __restrict__ src,
                                                   unsigned short* __restrict__ dst) {
  const int i = (blockIdx.x * 256 + threadIdx.x) * 8;
  const float4 a = *(const float4*)(src + i);
  const float4 b = *(const float4*)(src + i + 4);
  short8v o;
  o[0] = (short)f2bf(a.x); o[1] = (short)f2bf(a.y); o[2] = (short)f2bf(a.z); o[3] = (short)f2bf(a.w);
  o[4] = (short)f2bf(b.x); o[5] = (short)f2bf(b.y); o[6] = (short)f2bf(b.z); o[7] = (short)f2bf(b.w);
  *(short8v*)(dst + i) = o;
}

// ------------- transpose+cast weights: f32 [R][C] -> bf16 [C][R] -------------
__global__ __launch_bounds__(256) void trc_kernel(const float* __restrict__ src,
                                                  unsigned short* __restrict__ dst,
                                                  int R, int C) {
  const int t = threadIdx.x;
  const int r0 = blockIdx.y * 128, c0 = blockIdx.x * 128;
  const int rb = (t >> 4) * 8, cb2 = (t & 15) * 8;
  float vreg[8][8];
#pragma unroll
  for (int u = 0; u < 8; ++u) {
    const float4 p0 = *(const float4*)(src + (size_t)(r0 + rb + u) * C + c0 + cb2);
    const float4 p1 = *(const float4*)(src + (size_t)(r0 + rb + u) * C + c0 + cb2 + 4);
    vreg[u][0] = p0.x; vreg[u][1] = p0.y; vreg[u][2] = p0.z; vreg[u][3] = p0.w;
    vreg[u][4] = p1.x; vreg[u][5] = p1.y; vreg[u][6] = p1.z; vreg[u][7] = p1.w;
  }
#pragma unroll
  for (int j = 0; j < 8; ++j) {
    short8v o;
#pragma unroll
    for (int u = 0; u < 8; ++u) o[u] = (short)f2bf(vreg[u][j]);
    *(short8v*)(dst + (size_t)(c0 + cb2 + j) * R + r0 + rb) = o;
  }
}

// ------------- v bf16 [4096][2048] -> vT bf16 [8][512][2048] -------------
__global__ __launch_bounds__(256) void trv_kernel(const unsigned short* __restrict__ v,
                                                  unsigned short* __restrict__ vt) {
  const int t = threadIdx.x;
  const int s0 = blockIdx.x * 128;
  const int d0 = blockIdx.y * 128;
  const int bn = blockIdx.z;
  const int b = bn >> 2, n = bn & 3;
  const int sb = (t >> 4) * 8, db = (t & 15) * 8;
  unsigned short r[8][8];
#pragma unroll
  for (int u = 0; u < 8; ++u) {
    const short8v x2 = *(const short8v*)(v + (size_t)(b * S_LEN + s0 + sb + u) * INNERD + n * DHEAD + d0 + db);
#pragma unroll
    for (int j = 0; j < 8; ++j) r[u][j] = (unsigned short)x2[j];
  }
#pragma unroll
  for (int j = 0; j < 8; ++j) {
    short8v o;
#pragma unroll
    for (int u = 0; u < 8; ++u) o[u] = (short)r[u][j];
    *(short8v*)(vt + (size_t)(bn * DHEAD + d0 + db + j) * S_LEN + s0 + sb) = o;
  }
}

// ---------------- bf16 MFMA GEMM: C[M,N] = A[M,K] * Bt[N,K]^T ----------------
// 128x128 tile, 256 thr (4 waves 2x2), BK=64, swizzled LDS via global_load_lds.
// OUTMODE 0: f32 C. OUTMODE 1: bf16 split at col 2048 into Cb0/Cb1.
template <int OUTMODE>
__global__ __launch_bounds__(256) void gemm_bf16(const unsigned short* __restrict__ A,
                                                 const unsigned short* __restrict__ Bt,
                                                 float* __restrict__ Cf,
                                                 unsigned short* __restrict__ Cb0,
                                                 unsigned short* __restrict__ Cb1,
                                                 int M, int N, int K) {
  __shared__ unsigned short As[128 * 64];
  __shared__ unsigned short Bs[128 * 64];
  const int tid = threadIdx.x;
  const int w = tid >> 6, l = tid & 63;
  const int lm = l & 15, l4 = l >> 4, l8 = l & 7, lr = l >> 3;
  const int nwg = gridDim.x * gridDim.y;
  int bid = blockIdx.y * gridDim.x + blockIdx.x;
  const int cpx = nwg >> 3;
  bid = (bid & 7) * cpx + (bid >> 3);  // XCD swizzle (nwg % 8 == 0)
  const int bx = bid % gridDim.x, by = bid / gridDim.x;
  const int row0 = by * 128, col0 = bx * 128;
  const int wm = w >> 1, wn = w & 1;
  f32x4 acc[16];
#pragma unroll
  for (int i2 = 0; i2 < 16; ++i2) acc[i2] = (f32x4){0.f, 0.f, 0.f, 0.f};

  const int scol = (l8 * 16) ^ (lr << 4);  // pre-swizzled source byte col

  for (int k0 = 0; k0 < K; k0 += 64) {
#pragma unroll
    for (int it = 0; it < 4; ++it) {
      const int r = it * 32 + w * 8 + lr;
      gll16((const char*)A + ((size_t)(row0 + r) * K + k0) * 2 + scol,
            (char*)As + (size_t)(it * 32 + w * 8) * 128);
      gll16((const char*)Bt + ((size_t)(col0 + r) * K + k0) * 2 + scol,
            (char*)Bs + (size_t)(it * 32 + w * 8) * 128);
    }
    __syncthreads();
#pragma unroll
    for (int ks = 0; ks < 2; ++ks) {
      short8v af[4], bfr[4];
#pragma unroll
      for (int rb = 0; rb < 4; ++rb) {
        const int row = wm * 64 + rb * 16 + lm;
        af[rb] = *(const short8v*)((const char*)As + row * 128 + ((ks * 64 + l4 * 16) ^ ((lm & 7) << 4)));
      }
#pragma unroll
      for (int cb = 0; cb < 4; ++cb) {
        const int row = wn * 64 + cb * 16 + lm;
        bfr[cb] = *(const short8v*)((const char*)Bs + row * 128 + ((ks * 64 + l4 * 16) ^ ((lm & 7) << 4)));
      }
#pragma unroll
      for (int rb = 0; rb < 4; ++rb)
#pragma unroll
        for (int cb = 0; cb < 4; ++cb)
          acc[rb * 4 + cb] = MFMA_BF16(af[rb], bfr[cb], acc[rb * 4 + cb]);
    }
    __syncthreads();
  }
#pragma unroll
  for (int rb = 0; rb < 4; ++rb)
#pragma unroll
    for (int cb = 0; cb < 4; ++cb)
#pragma unroll
      for (int r = 0; r < 4; ++r) {
        const int gr = row0 + wm * 64 + rb * 16 + l4 * 4 + r;
        const int gc = col0 + wn * 64 + cb * 16 + lm;
        const float vv = acc[rb * 4 + cb][r];
        if (OUTMODE == 0) {
          Cf[(size_t)gr * N + gc] = vv;
        } else {
          if (gc < 2048) Cb0[(size_t)gr * 2048 + gc] = f2bf(vv);
          else Cb1[(size_t)gr * 2048 + gc - 2048] = f2bf(vv);
        }
      }
}

// ------- headwise: conv recompute + swish, 4x4 q/k/v proj (bf16 out), gates -------
__global__ __launch_bounds__(256) void headwise_kernel(
    const unsigned short* __restrict__ xm,
    const float* __restrict__ cw, const float* __restrict__ cbias,
    const float* __restrict__ Wq, const float* __restrict__ Wk, const float* __restrict__ Wv,
    const float* __restrict__ Wig, const float* __restrict__ big,
    const float* __restrict__ Wfg, const float* __restrict__ bfg,
    unsigned short* __restrict__ q, unsigned short* __restrict__ k, unsigned short* __restrict__ v,
    float* __restrict__ igpre, float* __restrict__ fgpre) {
  __shared__ float red[8][264];
  const int bs = blockIdx.x;
  const int s = bs & (S_LEN - 1);
  const int t = threadIdx.x;
  const int c0 = t * 8;
  float xa8[8], xm8[8];
  {
    float accv[8];
#pragma unroll
    for (int u = 0; u < 8; ++u) accv[u] = cbias[c0 + u];
#pragma unroll
    for (int i2 = 0; i2 < 4; ++i2) {
      const int sj = s - 3 + i2;
      if (sj >= 0) {
        const short8v xv = *(const short8v*)(xm + (size_t)(bs - 3 + i2) * INNERD + c0);
#pragma unroll
        for (int u = 0; u < 8; ++u)
          accv[u] += bf2f((unsigned short)xv[u]) * cw[i2 * INNERD + c0 + u];
      }
    }
    const short8v xs = *(const short8v*)(xm + (size_t)bs * INNERD + c0);
#pragma unroll
    for (int u = 0; u < 8; ++u) { xm8[u] = bf2f((unsigned short)xs[u]); xa8[u] = swishf(accv[u]); }
  }
  float iga[4] = {0, 0, 0, 0}, fga[4] = {0, 0, 0, 0};
  short8v qo, ko, vo;
#pragma unroll
  for (int hh = 0; hh < 2; ++hh) {
    const int h = t * 2 + hh;
    float qv[4], kv[4], vv[4];
#pragma unroll
    for (int o = 0; o < 4; ++o) {
      const float4 wq = *(const float4*)(Wq + (size_t)(h * 4 + o) * 4);
      const float4 wk = *(const float4*)(Wk + (size_t)(h * 4 + o) * 4);
      const float4 wv = *(const float4*)(Wv + (size_t)(h * 4 + o) * 4);
      qv[o] = wq.x * xa8[hh * 4] + wq.y * xa8[hh * 4 + 1] + wq.z * xa8[hh * 4 + 2] + wq.w * xa8[hh * 4 + 3];
      kv[o] = wk.x * xa8[hh * 4] + wk.y * xa8[hh * 4 + 1] + wk.z * xa8[hh * 4 + 2] + wk.w * xa8[hh * 4 + 3];
      vv[o] = wv.x * xm8[hh * 4] + wv.y * xm8[hh * 4 + 1] + wv.z * xm8[hh * 4 + 2] + wv.w * xm8[hh * 4 + 3];
      qo[hh * 4 + o] = (short)f2bf(qv[o]);
      ko[hh * 4 + o] = (short)f2bf(kv[o]);
      vo[hh * 4 + o] = (short)f2bf(vv[o]);
    }
#pragma unroll
    for (int o = 0; o < 4; ++o) {
      const int j0 = h * 4 + o;
      const float4 wi0 = *(const float4*)(Wig + (size_t)j0 * 4);
      const float4 wi1 = *(const float4*)(Wig + (size_t)(INNERD + j0) * 4);
      const float4 wi2 = *(const float4*)(Wig + (size_t)(2 * INNERD + j0) * 4);
      iga[0] += qv[o] * wi0.x + kv[o] * wi1.x + vv[o] * wi2.x;
      iga[1] += qv[o] * wi0.y + kv[o] * wi1.y + vv[o] * wi2.y;
      iga[2] += qv[o] * wi0.z + kv[o] * wi1.z + vv[o] * wi2.z;
      iga[3] += qv[o] * wi0.w + kv[o] * wi1.w + vv[o] * wi2.w;
      const float4 wf0 = *(const float4*)(Wfg + (size_t)j0 * 4);
      const float4 wf1 = *(const float4*)(Wfg + (size_t)(INNERD + j0) * 4);
      const float4 wf2 = *(const float4*)(Wfg + (size_t)(2 * INNERD + j0) * 4);
      fga[0] += qv[o] * wf0.x + kv[o] * wf1.x + vv[o] * wf2.x;
      fga[1] += qv[o] * wf0.y + kv[o] * wf1.y + vv[o] * wf2.y;
      fga[2] += qv[o] * wf0.z + kv[o] * wf1.z + vv[o] * wf2.z;
      fga[3] += qv[o] * wf0.w + kv[o] * wf1.w + vv[o] * wf2.w;
    }
  }
  *(short8v*)(q + (size_t)bs * INNERD + c0) = qo;
  *(short8v*)(k + (size_t)bs * INNERD + c0) = ko;
  *(short8v*)(v + (size_t)bs * INNERD + c0) = vo;
#pragma unroll
  for (int g = 0; g < 4; ++g) { red[g][t] = iga[g]; red[g + 4][t] = fga[g]; }
  __syncthreads();
  for (int off = 128; off >= 1; off >>= 1) {
    if (t < off) {
#pragma unroll
      for (int g = 0; g < 8; ++g) red[g][t] += red[g][t + off];
    }
    __syncthreads();
  }
  if (t < 4) {
    const int b = bs >> 11;
    igpre[((size_t)(b * NHEAD + t)) * S_LEN + s] = red[t][0] + big[t];
  } else if (t < 8) {
    const int b = bs >> 11;
    fgpre[((size_t)(b * NHEAD + (t - 4))) * S_LEN + s] = red[t][0] + bfg[t - 4];
  }
}

// -------- per-(b,n) scan: L=cumsum(logsig(fg)), a=ig-L, rm=runmax(a), e=exp(-(L+rm))
__global__ __launch_bounds__(256) void scan_kernel(const float* __restrict__ igpre,
                                                   const float* __restrict__ fgpre,
                                                   float* __restrict__ a_o,
                                                   float* __restrict__ rm_o,
                                                   float* __restrict__ e_o) {
  __shared__ float sd[256];
  const int bn = blockIdx.x, t = threadIdx.x;
  const size_t base = (size_t)bn * S_LEN + t * 8;
  float cs[8];
  float run = 0.0f;
#pragma unroll
  for (int u = 0; u < 8; ++u) { run += logsigf(fgpre[base + u]); cs[u] = run; }
  sd[t] = run;
  __syncthreads();
  for (int off = 1; off < 256; off <<= 1) {
    const float vv2 = (t >= off) ? sd[t - off] : 0.0f;
    __syncthreads();
    sd[t] += vv2;
    __syncthreads();
  }
  const float exs = (t > 0) ? sd[t - 1] : 0.0f;
  __syncthreads();
  float av[8], pm[8];
  float rmax = -INFINITY;
#pragma unroll
  for (int u = 0; u < 8; ++u) {
    const float L = exs + cs[u];
    cs[u] = L;
    av[u] = igpre[base + u] - L;
    rmax = fmaxf(rmax, av[u]);
    pm[u] = rmax;
  }
  sd[t] = rmax;
  __syncthreads();
  for (int off = 1; off < 256; off <<= 1) {
    const float vv2 = (t >= off) ? sd[t - off] : -INFINITY;
    __syncthreads();
    sd[t] = fmaxf(sd[t], vv2);
    __syncthreads();
  }
  const float exm = (t > 0) ? sd[t - 1] : -INFINITY;
#pragma unroll
  for (int u = 0; u < 8; ++u) {
    const float rmv = fmaxf(exm, pm[u]);
    a_o[base + u] = av[u];
    rm_o[base + u] = rmv;
    e_o[base + u] = expf(-(cs[u] + rmv));
  }
}

// ---------------- mLSTM core: MFMA flash-style, BQ=64, BJ=64, 8 waves ----------
__global__ __launch_bounds__(512) void mlstm_mfma(
    const unsigned short* __restrict__ qg, const unsigned short* __restrict__ kg,
    const unsigned short* __restrict__ vtg,
    const float* __restrict__ ag, const float* __restrict__ rmg,
    float* __restrict__ hraw, float* __restrict__ rsumg) {
  __shared__ unsigned short Ks[64 * 512];  // 64KB, 1024B rows, XOR (row&7)<<4
  __shared__ unsigned short Ps[64 * 64];   // 8KB, 128B rows, XOR (row&7)<<4
  const int tid = threadIdx.x;
  const int w = tid >> 6, l = tid & 63;
  const int lm = l & 15, l4 = l >> 4;
  const int bid = blockIdx.x;
  const int bn = bid & 7;
  const int rest = bid >> 3;
  const int part = rest & 1;
  const int qi = 31 - (rest >> 1);  // longest blocks dispatched first
  const int i0 = qi << 6;
  const int b = bn >> 2, n = bn & 3;

  // Q fragments in registers: wave's row-block = w>>1
  const int rA = ((w >> 1) << 4) + lm;
  short8v qf[16];
  {
    const unsigned short* qp = qg + (size_t)(b * S_LEN + i0 + rA) * INNERD + n * DHEAD + l4 * 8;
#pragma unroll
    for (int ks = 0; ks < 16; ++ks) qf[ks] = *(const short8v*)(qp + ks * 32);
  }
  const int rD = ((w >> 1) << 4) + (l4 << 2);  // D-layout rows rD..rD+3
  float rm4[4];
#pragma unroll
  for (int r = 0; r < 4; ++r) rm4[r] = rmg[(size_t)bn * S_LEN + i0 + rD + r];
  const int cb0 = (w & 1) << 1;

  f32x4 acc[16];
#pragma unroll
  for (int i2 = 0; i2 < 16; ++i2) acc[i2] = (f32x4){0.f, 0.f, 0.f, 0.f};
  float rs4[4] = {0.f, 0.f, 0.f, 0.f};

  const int Tn = qi + 1;
  for (int jt = part; jt < Tn; jt += 2) {
    const int j0 = jt << 6;
    // V B-fragments direct from L2 (vT layout: contiguous in j)
    short8v vf[8];
#pragma unroll
    for (int db = 0; db < 4; ++db)
#pragma unroll
      for (int ks = 0; ks < 2; ++ks)
        vf[db * 2 + ks] = *(const short8v*)(vtg + (size_t)(bn * DHEAD + w * 64 + db * 16 + lm) * S_LEN + j0 + ks * 32 + l4 * 8);
    const float a0 = ag[(size_t)bn * S_LEN + j0 + cb0 * 16 + lm];
    const float a1 = ag[(size_t)bn * S_LEN + j0 + cb0 * 16 + 16 + lm];
    // stage K tile (pre-swizzled source -> linear LDS dest)
#pragma unroll
    for (int it = 0; it < 8; ++it) {
      const int row = it * 8 + w;
      gll16((const char*)kg + ((size_t)(b * S_LEN + j0 + row) * INNERD + n * DHEAD) * 2 + ((l * 16) ^ ((row & 7) << 4)),
            (char*)Ks + row * 1024);
    }
    __syncthreads();
    // QK^T: 2 S-frags per wave (cblks cb0, cb0+1)
    f32x4 s0 = (f32x4){0.f, 0.f, 0.f, 0.f}, s1 = (f32x4){0.f, 0.f, 0.f, 0.f};
#pragma unroll
    for (int ks = 0; ks < 16; ++ks) {
      const short8v b0 = *(const short8v*)((const char*)Ks + (cb0 * 16 + lm) * 1024 + ((ks * 64 + l4 * 16) ^ ((lm & 7) << 4)));
      const short8v b1 = *(const short8v*)((const char*)Ks + ((cb0 + 1) * 16 + lm) * 1024 + ((ks * 64 + l4 * 16) ^ ((lm & 7) << 4)));
      s0 = MFMA_BF16(qf[ks], b0, s0);
      s1 = MFMA_BF16(qf[ks], b1, s1);
    }
    // gate + causal mask + rowsum + write P (bf16, swizzled)
#pragma unroll
    for (int half = 0; half < 2; ++half) {
      const f32x4 sv = half ? s1 : s0;
      const float av = half ? a1 : a0;
      const int jl = (cb0 + half) * 16 + lm;
#pragma unroll
      for (int r = 0; r < 4; ++r) {
        const int il = rD + r;
        const float es = __expf(av - rm4[r]);
        const float p = (j0 + jl <= i0 + il) ? sv[r] * SCALE_QK * es : 0.0f;
        rs4[r] += p;
        *((unsigned short*)((char*)Ps + il * 128 + ((jl * 2) ^ ((il & 7) << 4)))) = f2bf(p);
      }
    }
    __syncthreads();
    // PV: acc[rb][db] (64 rows x 64-d chunk per wave, wd = w)
#pragma unroll
    for (int ks = 0; ks < 2; ++ks) {
      short8v pa[4];
#pragma unroll
      for (int rb = 0; rb < 4; ++rb)
        pa[rb] = *(const short8v*)((const char*)Ps + (rb * 16 + lm) * 128 + ((ks * 64 + l4 * 16) ^ ((lm & 7) << 4)));
#pragma unroll
      for (int rb = 0; rb < 4; ++rb)
#pragma unroll
        for (int db = 0; db < 4; ++db)
          acc[rb * 4 + db] = MFMA_BF16(pa[rb], vf[db * 2 + ks], acc[rb * 4 + db]);
    }
    __syncthreads();
  }
  // rowsum: reduce over 16 column-lanes, then atomic combine (2 waves + 2 parts)
#pragma unroll
  for (int r = 0; r < 4; ++r) {
    float v2 = rs4[r];
    v2 += __shfl_xor(v2, 1, 64);
    v2 += __shfl_xor(v2, 2, 64);
    v2 += __shfl_xor(v2, 4, 64);
    v2 += __shfl_xor(v2, 8, 64);
    if (lm == 0) atomicAdd(&rsumg[(size_t)bn * S_LEN + i0 + rD + r], v2);
  }
  // raw h combine
#pragma unroll
  for (int rb = 0; rb < 4; ++rb)
#pragma unroll
    for (int db = 0; db < 4; ++db)
#pragma unroll
      for (int r = 0; r < 4; ++r)
        atomicAdd(&hraw[(size_t)(b * S_LEN + i0 + rb * 16 + l4 * 4 + r) * INNERD + n * DHEAD + w * 64 + db * 16 + lm],
                  acc[rb * 4 + db][r]);
}

// ------- mhln: norm-divide + multi-head LN + conv-recompute skip + swish(z), bf16 out -------
__global__ __launch_bounds__(256) void mhln_kernel(
    const float* __restrict__ h, const unsigned short* __restrict__ xm,
    const unsigned short* __restrict__ zb,
    const float* __restrict__ cw, const float* __restrict__ cbias,
    const float* __restrict__ rsumg, const float* __restrict__ eg,
    const float* __restrict__ normw, const float* __restrict__ skip,
    unsigned short* __restrict__ hstate) {
  const int bs = blockIdx.x, t = threadIdx.x;
  const int bb = bs >> 11, s = bs & (S_LEN - 1);
  const int n = t >> 6, lane = t & 63;
  const int cp0 = n * DHEAD + lane * 8;
  const size_t hb = (size_t)bs * INNERD + cp0;
  const int bn = bb * NHEAD + n;
  const float rsv = rsumg[(size_t)bn * S_LEN + s];
  const float ev = eg[(size_t)bn * S_LEN + s];
  const float inorm = 1.0f / (fmaxf(fabsf(rsv), ev) + 1e-6f);
  const float4 v0 = *(const float4*)(h + hb);
  const float4 v1 = *(const float4*)(h + hb + 4);
  float vals[8] = {v0.x * inorm, v0.y * inorm, v0.z * inorm, v0.w * inorm,
                   v1.x * inorm, v1.y * inorm, v1.z * inorm, v1.w * inorm};
  float sum = 0.0f;
#pragma unroll
  for (int u = 0; u < 8; ++u) sum += vals[u];
#pragma unroll
  for (int m = 32; m >= 1; m >>= 1) sum += __shfl_xor(sum, m, 64);
  const float mu = sum * (1.0f / 512.0f);
  float vs2 = 0.0f;
#pragma unroll
  for (int u = 0; u < 8; ++u) { const float d = vals[u] - mu; vs2 += d * d; }
#pragma unroll
  for (int m = 32; m >= 1; m >>= 1) vs2 += __shfl_xor(vs2, m, 64);
  const float rstd = rsqrtf(vs2 * (1.0f / 512.0f) + 1e-6f);
  // conv recompute for skip path
  float xa8[8];
  {
    float accv[8];
#pragma unroll
    for (int u = 0; u < 8; ++u) accv[u] = cbias[cp0 + u];
#pragma unroll
    for (int i2 = 0; i2 < 4; ++i2) {
      const int sj = s - 3 + i2;
      if (sj >= 0) {
        const short8v xv = *(const short8v*)(xm + (size_t)(bs - 3 + i2) * INNERD + cp0);
#pragma unroll
        for (int u = 0; u < 8; ++u)
          accv[u] += bf2f((unsigned short)xv[u]) * cw[i2 * INNERD + cp0 + u];
      }
    }
#pragma unroll
    for (int u = 0; u < 8; ++u) xa8[u] = swishf(accv[u]);
  }
  const short8v zv = *(const short8v*)(zb + (size_t)bs * INNERD + cp0);
  short8v o;
#pragma unroll
  for (int u = 0; u < 8; ++u) {
    const int cp = cp0 + u;
    const float hn = (vals[u] - mu) * rstd * normw[cp];
    const float z = bf2f((unsigned short)zv[u]);
    o[u] = (short)f2bf((hn + skip[cp] * xa8[u]) * swishf(z));
  }
  *(short8v*)(hstate + hb) = o;
}

extern "C" void kernel_launch(void* const* d_in, const int* in_sizes, int n_in,
                              void* d_out, int out_size, void* d_ws, size_t ws_size,
                              hipStream_t stream) {
  const float* x     = (const float*)d_in[0];
  const float* Wup   = (const float*)d_in[1];
  const float* cw    = (const float*)d_in[2];
  const float* cb    = (const float*)d_in[3];
  const float* Wq    = (const float*)d_in[4];
  const float* Wk    = (const float*)d_in[5];
  const float* Wv    = (const float*)d_in[6];
  const float* Wig   = (const float*)d_in[7];
  const float* big   = (const float*)d_in[8];
  const float* Wfg   = (const float*)d_in[9];
  const float* bfg   = (const float*)d_in[10];
  const float* normw = (const float*)d_in[11];
  const float* skip  = (const float*)d_in[12];
  const float* Wdown = (const float*)d_in[13];
  float* out = (float*)d_out;

  float* ws = (float*)d_ws;
  size_t off = 0;
  const size_t MR = (size_t)BATCH * S_LEN;  // 4096
  unsigned short* xm  = (unsigned short*)(ws + off); off += MR * INNERD / 2;   // 4.19M f32u
  unsigned short* zb  = (unsigned short*)(ws + off); off += MR * INNERD / 2;
  float* hraw         = ws + off;                    off += MR * INNERD;        // 8.39M
  unsigned short* qb  = (unsigned short*)(ws + off); off += MR * INNERD / 2;
  unsigned short* kb  = (unsigned short*)(ws + off); off += MR * INNERD / 2;
  unsigned short* vt  = (unsigned short*)(ws + off); off += MR * INNERD / 2;
  float* igpre  = ws + off; off += (size_t)BATCH * NHEAD * S_LEN;
  float* fgpre  = ws + off; off += (size_t)BATCH * NHEAD * S_LEN;
  float* a_buf  = ws + off; off += (size_t)BATCH * NHEAD * S_LEN;
  float* rm_buf = ws + off; off += (size_t)BATCH * NHEAD * S_LEN;
  float* e_buf  = ws + off; off += (size_t)BATCH * NHEAD * S_LEN;
  float* rsum   = ws + off; off += (size_t)BATCH * NHEAD * S_LEN;
  if (ws_size < off * sizeof(float)) return;

  // aliases into dead regions
  unsigned short* vb     = (unsigned short*)hraw;                 // v bf16, dead before memset(hraw)
  unsigned short* x_bf   = (unsigned short*)(hraw + MR * INNERD / 2);  // x bf16
  unsigned short* WupT   = vt;                                    // dead before trv writes vt
  unsigned short* WdT    = kb;                                    // dead after mlstm
  unsigned short* hstate = qb;                                    // dead after mlstm

  cast_kernel<<<2048, 256, 0, stream>>>(x, x_bf);                       // 4096x1024
  trc_kernel<<<dim3(32, 8), 256, 0, stream>>>(Wup, WupT, 1024, 4096);   // -> [4096][1024]
  gemm_bf16<1><<<dim3(32, 32), 256, 0, stream>>>(x_bf, WupT, nullptr, xm, zb, 4096, 4096, 1024);
  headwise_kernel<<<4096, 256, 0, stream>>>(xm, cw, cb, Wq, Wk, Wv, Wig, big, Wfg, bfg,
                                            qb, kb, vb, igpre, fgpre);
  trv_kernel<<<dim3(16, 4, 8), 256, 0, stream>>>(vb, vt);
  scan_kernel<<<8, 256, 0, stream>>>(igpre, fgpre, a_buf, rm_buf, e_buf);
  hipMemsetAsync(hraw, 0, MR * INNERD * sizeof(float), stream);
  hipMemsetAsync(rsum, 0, (size_t)BATCH * NHEAD * S_LEN * sizeof(float), stream);
  mlstm_mfma<<<512, 512, 0, stream>>>(qb, kb, vt, a_buf, rm_buf, hraw, rsum);
  trc_kernel<<<dim3(8, 16), 256, 0, stream>>>(Wdown, WdT, 2048, 1024);  // -> [1024][2048]
  mhln_kernel<<<4096, 256, 0, stream>>>(hraw, xm, zb, cw, cb, rsum, e_buf, normw, skip, hstate);
  gemm_bf16<0><<<dim3(8, 32), 256, 0, stream>>>(hstate, WdT, out, nullptr, nullptr, 4096, 1024, 2048);
}

// Round 3
// 508.037 us; speedup vs baseline: 7.1842x; 1.1715x over previous
//
#include <hip/hip_runtime.h>
#include <math.h>

#define S_LEN 2048
#define INNERD 2048
#define NHEAD 4
#define DHEAD 512
#define BATCH 2
#define SCALE_QK 0.044194173824159216f

typedef __attribute__((ext_vector_type(8))) short short8v;
typedef __attribute__((ext_vector_type(4))) float f32x4;

#define MFMA_BF16(A, B, C) __builtin_amdgcn_mfma_f32_16x16x32_bf16(A, B, C, 0, 0, 0)

__device__ __forceinline__ void gll16(const void* g, void* l) {
  __builtin_amdgcn_global_load_lds((const __attribute__((address_space(1))) unsigned int*)g,
                                   (__attribute__((address_space(3))) unsigned int*)l,
                                   16, 0, 0);
}

__device__ __forceinline__ unsigned short f2bf(float x) {
  union { float f; unsigned u; } v; v.f = x;
  unsigned r = v.u + 0x7FFFu + ((v.u >> 16) & 1u);
  return (unsigned short)(r >> 16);
}
__device__ __forceinline__ float bf2f(unsigned short x) {
  union { unsigned u; float f; } v; v.u = ((unsigned)x) << 16; return v.f;
}
__device__ __forceinline__ float swishf(float x) { return x / (1.0f + __expf(-x)); }
__device__ __forceinline__ float logsigf(float x) {
  return (x >= 0.0f) ? -log1pf(expf(-x)) : (x - log1pf(expf(x)));
}

// ---------------- cast f32 -> bf16 (8 elems/thread) ----------------
__global__ __launch_bounds__(256) void cast_kernel(const float* __restrict__ src,
                                                   unsigned short* __restrict__ dst) {
  const int i = (blockIdx.x * 256 + threadIdx.x) * 8;
  const float4 a = *(const float4*)(src + i);
  const float4 b = *(const float4*)(src + i + 4);
  short8v o;
  o[0] = (short)f2bf(a.x); o[1] = (short)f2bf(a.y); o[2] = (short)f2bf(a.z); o[3] = (short)f2bf(a.w);
  o[4] = (short)f2bf(b.x); o[5] = (short)f2bf(b.y); o[6] = (short)f2bf(b.z); o[7] = (short)f2bf(b.w);
  *(short8v*)(dst + i) = o;
}

// ------------- transpose+cast weights: f32 [R][C] -> bf16 [C][R] -------------
__global__ __launch_bounds__(256) void trc_kernel(const float* __restrict__ src,
                                                  unsigned short* __restrict__ dst,
                                                  int R, int C) {
  const int t = threadIdx.x;
  const int r0 = blockIdx.y * 128, c0 = blockIdx.x * 128;
  const int rb = (t >> 4) * 8, cb2 = (t & 15) * 8;
  float vreg[8][8];
#pragma unroll
  for (int u = 0; u < 8; ++u) {
    const float4 p0 = *(const float4*)(src + (size_t)(r0 + rb + u) * C + c0 + cb2);
    const float4 p1 = *(const float4*)(src + (size_t)(r0 + rb + u) * C + c0 + cb2 + 4);
    vreg[u][0] = p0.x; vreg[u][1] = p0.y; vreg[u][2] = p0.z; vreg[u][3] = p0.w;
    vreg[u][4] = p1.x; vreg[u][5] = p1.y; vreg[u][6] = p1.z; vreg[u][7] = p1.w;
  }
#pragma unroll
  for (int j = 0; j < 8; ++j) {
    short8v o;
#pragma unroll
    for (int u = 0; u < 8; ++u) o[u] = (short)f2bf(vreg[u][j]);
    *(short8v*)(dst + (size_t)(c0 + cb2 + j) * R + r0 + rb) = o;
  }
}

// ------------- v bf16 [4096][2048] -> vT bf16 [8][512][2048] -------------
__global__ __launch_bounds__(256) void trv_kernel(const unsigned short* __restrict__ v,
                                                  unsigned short* __restrict__ vt) {
  const int t = threadIdx.x;
  const int s0 = blockIdx.x * 128;
  const int d0 = blockIdx.y * 128;
  const int bn = blockIdx.z;
  const int b = bn >> 2, n = bn & 3;
  const int sb = (t >> 4) * 8, db = (t & 15) * 8;
  unsigned short r[8][8];
#pragma unroll
  for (int u = 0; u < 8; ++u) {
    const short8v x2 = *(const short8v*)(v + (size_t)(b * S_LEN + s0 + sb + u) * INNERD + n * DHEAD + d0 + db);
#pragma unroll
    for (int j = 0; j < 8; ++j) r[u][j] = (unsigned short)x2[j];
  }
#pragma unroll
  for (int j = 0; j < 8; ++j) {
    short8v o;
#pragma unroll
    for (int u = 0; u < 8; ++u) o[u] = (short)r[u][j];
    *(short8v*)(vt + (size_t)(bn * DHEAD + d0 + db + j) * S_LEN + s0 + sb) = o;
  }
}

// ------- prep: pack qkv weights bf16 per-thread + fold gate weights -------
// Wpk [12][256][8] bf16: chunks q(0..3) k(4..7) v(8..11); chunk = base + hh*2 + sub,
//   vals j: o = sub*2 + (j>>2), d = j&3.
// Cg f32 [4][2048][4]: 0=Ca_ig (applies to xa), 1=Cm_ig (xm), 2=Ca_fg, 3=Cm_fg.
__global__ __launch_bounds__(256) void prep_kernel(
    const float* __restrict__ Wq, const float* __restrict__ Wk, const float* __restrict__ Wv,
    const float* __restrict__ Wig, const float* __restrict__ Wfg,
    unsigned short* __restrict__ Wpk, float* __restrict__ Cg) {
  const int t = threadIdx.x;
  float wq[2][16], wk[2][16], wv[2][16];
#pragma unroll
  for (int hh = 0; hh < 2; ++hh) {
    const int h = 2 * t + hh;
#pragma unroll
    for (int j = 0; j < 16; ++j) {
      wq[hh][j] = Wq[(size_t)h * 16 + j];
      wk[hh][j] = Wk[(size_t)h * 16 + j];
      wv[hh][j] = Wv[(size_t)h * 16 + j];
    }
  }
#pragma unroll
  for (int hh = 0; hh < 2; ++hh)
#pragma unroll
    for (int sub = 0; sub < 2; ++sub) {
      short8v oq, ok, ov;
#pragma unroll
      for (int j = 0; j < 8; ++j) {
        oq[j] = (short)f2bf(wq[hh][sub * 8 + j]);
        ok[j] = (short)f2bf(wk[hh][sub * 8 + j]);
        ov[j] = (short)f2bf(wv[hh][sub * 8 + j]);
      }
      *(short8v*)(Wpk + ((size_t)(0 + hh * 2 + sub) * 256 + t) * 8) = oq;
      *(short8v*)(Wpk + ((size_t)(4 + hh * 2 + sub) * 256 + t) * 8) = ok;
      *(short8v*)(Wpk + ((size_t)(8 + hh * 2 + sub) * 256 + t) * 8) = ov;
    }
#pragma unroll
  for (int u = 0; u < 8; ++u) {
    const int hh = u >> 2, d = u & 3;
    const int h = 2 * t + hh;
    float cia[4] = {0, 0, 0, 0}, cim[4] = {0, 0, 0, 0};
    float cfa[4] = {0, 0, 0, 0}, cfm[4] = {0, 0, 0, 0};
#pragma unroll
    for (int o = 0; o < 4; ++o) {
      const int row = h * 4 + o;
      const float aq = wq[hh][o * 4 + d], ak = wk[hh][o * 4 + d], av = wv[hh][o * 4 + d];
#pragma unroll
      for (int g = 0; g < 4; ++g) {
        cia[g] += aq * Wig[(size_t)row * 4 + g] + ak * Wig[(size_t)(INNERD + row) * 4 + g];
        cim[g] += av * Wig[(size_t)(2 * INNERD + row) * 4 + g];
        cfa[g] += aq * Wfg[(size_t)row * 4 + g] + ak * Wfg[(size_t)(INNERD + row) * 4 + g];
        cfm[g] += av * Wfg[(size_t)(2 * INNERD + row) * 4 + g];
      }
    }
    const int c = t * 8 + u;
#pragma unroll
    for (int g = 0; g < 4; ++g) {
      Cg[((size_t)0 * INNERD + c) * 4 + g] = cia[g];
      Cg[((size_t)1 * INNERD + c) * 4 + g] = cim[g];
      Cg[((size_t)2 * INNERD + c) * 4 + g] = cfa[g];
      Cg[((size_t)3 * INNERD + c) * 4 + g] = cfm[g];
    }
  }
}

// ---------------- bf16 MFMA GEMM: C[M,N] = A[M,K] * Bt[N,K]^T ----------------
template <int OUTMODE>
__global__ __launch_bounds__(256) void gemm_bf16(const unsigned short* __restrict__ A,
                                                 const unsigned short* __restrict__ Bt,
                                                 float* __restrict__ Cf,
                                                 unsigned short* __restrict__ Cb0,
                                                 unsigned short* __restrict__ Cb1,
                                                 int M, int N, int K) {
  __shared__ unsigned short As[128 * 64];
  __shared__ unsigned short Bs[128 * 64];
  const int tid = threadIdx.x;
  const int w = tid >> 6, l = tid & 63;
  const int lm = l & 15, l4 = l >> 4, l8 = l & 7, lr = l >> 3;
  const int nwg = gridDim.x * gridDim.y;
  int bid = blockIdx.y * gridDim.x + blockIdx.x;
  const int cpx = nwg >> 3;
  bid = (bid & 7) * cpx + (bid >> 3);  // XCD swizzle (nwg % 8 == 0)
  const int bx = bid % gridDim.x, by = bid / gridDim.x;
  const int row0 = by * 128, col0 = bx * 128;
  const int wm = w >> 1, wn = w & 1;
  f32x4 acc[16];
#pragma unroll
  for (int i2 = 0; i2 < 16; ++i2) acc[i2] = (f32x4){0.f, 0.f, 0.f, 0.f};

  const int scol = (l8 * 16) ^ (lr << 4);

  for (int k0 = 0; k0 < K; k0 += 64) {
#pragma unroll
    for (int it = 0; it < 4; ++it) {
      const int r = it * 32 + w * 8 + lr;
      gll16((const char*)A + ((size_t)(row0 + r) * K + k0) * 2 + scol,
            (char*)As + (size_t)(it * 32 + w * 8) * 128);
      gll16((const char*)Bt + ((size_t)(col0 + r) * K + k0) * 2 + scol,
            (char*)Bs + (size_t)(it * 32 + w * 8) * 128);
    }
    __syncthreads();
#pragma unroll
    for (int ks = 0; ks < 2; ++ks) {
      short8v af[4], bfr[4];
#pragma unroll
      for (int rb = 0; rb < 4; ++rb) {
        const int row = wm * 64 + rb * 16 + lm;
        af[rb] = *(const short8v*)((const char*)As + row * 128 + ((ks * 64 + l4 * 16) ^ ((lm & 7) << 4)));
      }
#pragma unroll
      for (int cb = 0; cb < 4; ++cb) {
        const int row = wn * 64 + cb * 16 + lm;
        bfr[cb] = *(const short8v*)((const char*)Bs + row * 128 + ((ks * 64 + l4 * 16) ^ ((lm & 7) << 4)));
      }
#pragma unroll
      for (int rb = 0; rb < 4; ++rb)
#pragma unroll
        for (int cb = 0; cb < 4; ++cb)
          acc[rb * 4 + cb] = MFMA_BF16(af[rb], bfr[cb], acc[rb * 4 + cb]);
    }
    __syncthreads();
  }
#pragma unroll
  for (int rb = 0; rb < 4; ++rb)
#pragma unroll
    for (int cb = 0; cb < 4; ++cb)
#pragma unroll
      for (int r = 0; r < 4; ++r) {
        const int gr = row0 + wm * 64 + rb * 16 + l4 * 4 + r;
        const int gc = col0 + wn * 64 + cb * 16 + lm;
        const float vv = acc[rb * 4 + cb][r];
        if (OUTMODE == 0) {
          Cf[(size_t)gr * N + gc] = vv;
        } else {
          if (gc < 2048) Cb0[(size_t)gr * 2048 + gc] = f2bf(vv);
          else Cb1[(size_t)gr * 2048 + gc - 2048] = f2bf(vv);
        }
      }
}

// ------- headwise v2: conv + swish, packed qkv proj, folded gates -------
__global__ __launch_bounds__(256) void headwise_kernel(
    const unsigned short* __restrict__ xm,
    const unsigned short* __restrict__ Wpk, const float* __restrict__ Cg,
    const float* __restrict__ cw, const float* __restrict__ cbias,
    const float* __restrict__ big, const float* __restrict__ bfg,
    unsigned short* __restrict__ q, unsigned short* __restrict__ k,
    unsigned short* __restrict__ v,
    float* __restrict__ igpre, float* __restrict__ fgpre) {
  __shared__ float red2[4][8];
  const int bs = blockIdx.x, t = threadIdx.x;
  const int s = bs & (S_LEN - 1);
  const int c0 = t * 8;
  float xa8[8], xm8[8];
  {
    float accv[8];
    const float4 cb0 = *(const float4*)(cbias + c0);
    const float4 cb1 = *(const float4*)(cbias + c0 + 4);
    accv[0] = cb0.x; accv[1] = cb0.y; accv[2] = cb0.z; accv[3] = cb0.w;
    accv[4] = cb1.x; accv[5] = cb1.y; accv[6] = cb1.z; accv[7] = cb1.w;
#pragma unroll
    for (int i = 0; i < 4; ++i) {
      if (s - 3 + i >= 0) {
        const short8v xv = *(const short8v*)(xm + (size_t)(bs - 3 + i) * INNERD + c0);
        const float4 w0 = *(const float4*)(cw + i * INNERD + c0);
        const float4 w1 = *(const float4*)(cw + i * INNERD + c0 + 4);
        const float wv2[8] = {w0.x, w0.y, w0.z, w0.w, w1.x, w1.y, w1.z, w1.w};
#pragma unroll
        for (int u = 0; u < 8; ++u) accv[u] += bf2f((unsigned short)xv[u]) * wv2[u];
      }
    }
    const short8v xs = *(const short8v*)(xm + (size_t)bs * INNERD + c0);
#pragma unroll
    for (int u = 0; u < 8; ++u) { xm8[u] = bf2f((unsigned short)xs[u]); xa8[u] = swishf(accv[u]); }
  }
  short8v qo, ko, vo;
#pragma unroll
  for (int hh = 0; hh < 2; ++hh)
#pragma unroll
    for (int sub = 0; sub < 2; ++sub) {
      const short8v wq = *(const short8v*)(Wpk + ((size_t)(0 + hh * 2 + sub) * 256 + t) * 8);
      const short8v wk = *(const short8v*)(Wpk + ((size_t)(4 + hh * 2 + sub) * 256 + t) * 8);
      const short8v wv3 = *(const short8v*)(Wpk + ((size_t)(8 + hh * 2 + sub) * 256 + t) * 8);
      float ql = 0, qh = 0, kl = 0, kh2 = 0, vl = 0, vh = 0;
#pragma unroll
      for (int d = 0; d < 4; ++d) {
        const float xa = xa8[hh * 4 + d], xv2 = xm8[hh * 4 + d];
        ql += bf2f((unsigned short)wq[d]) * xa;
        qh += bf2f((unsigned short)wq[4 + d]) * xa;
        kl += bf2f((unsigned short)wk[d]) * xa;
        kh2 += bf2f((unsigned short)wk[4 + d]) * xa;
        vl += bf2f((unsigned short)wv3[d]) * xv2;
        vh += bf2f((unsigned short)wv3[4 + d]) * xv2;
      }
      qo[hh * 4 + sub * 2] = (short)f2bf(ql); qo[hh * 4 + sub * 2 + 1] = (short)f2bf(qh);
      ko[hh * 4 + sub * 2] = (short)f2bf(kl); ko[hh * 4 + sub * 2 + 1] = (short)f2bf(kh2);
      vo[hh * 4 + sub * 2] = (short)f2bf(vl); vo[hh * 4 + sub * 2 + 1] = (short)f2bf(vh);
    }
  *(short8v*)(q + (size_t)bs * INNERD + c0) = qo;
  *(short8v*)(k + (size_t)bs * INNERD + c0) = ko;
  *(short8v*)(v + (size_t)bs * INNERD + c0) = vo;
  float r8[8] = {0, 0, 0, 0, 0, 0, 0, 0};
#pragma unroll
  for (int u = 0; u < 8; ++u) {
    const float4 cia = *(const float4*)(Cg + ((size_t)0 * INNERD + c0 + u) * 4);
    const float4 cim = *(const float4*)(Cg + ((size_t)1 * INNERD + c0 + u) * 4);
    const float4 cfa = *(const float4*)(Cg + ((size_t)2 * INNERD + c0 + u) * 4);
    const float4 cfm = *(const float4*)(Cg + ((size_t)3 * INNERD + c0 + u) * 4);
    r8[0] += xa8[u] * cia.x + xm8[u] * cim.x;
    r8[1] += xa8[u] * cia.y + xm8[u] * cim.y;
    r8[2] += xa8[u] * cia.z + xm8[u] * cim.z;
    r8[3] += xa8[u] * cia.w + xm8[u] * cim.w;
    r8[4] += xa8[u] * cfa.x + xm8[u] * cfm.x;
    r8[5] += xa8[u] * cfa.y + xm8[u] * cfm.y;
    r8[6] += xa8[u] * cfa.z + xm8[u] * cfm.z;
    r8[7] += xa8[u] * cfa.w + xm8[u] * cfm.w;
  }
#pragma unroll
  for (int v2 = 0; v2 < 8; ++v2) {
    r8[v2] += __shfl_xor(r8[v2], 1, 64);
    r8[v2] += __shfl_xor(r8[v2], 2, 64);
    r8[v2] += __shfl_xor(r8[v2], 4, 64);
    r8[v2] += __shfl_xor(r8[v2], 8, 64);
    r8[v2] += __shfl_xor(r8[v2], 16, 64);
    r8[v2] += __shfl_xor(r8[v2], 32, 64);
  }
  if ((t & 63) == 0) {
#pragma unroll
    for (int v2 = 0; v2 < 8; ++v2) red2[t >> 6][v2] = r8[v2];
  }
  __syncthreads();
  if (t < 8) {
    const float sum = red2[0][t] + red2[1][t] + red2[2][t] + red2[3][t];
    const int b = bs >> 11;
    if (t < 4) igpre[((size_t)(b * NHEAD + t)) * S_LEN + s] = sum + big[t];
    else fgpre[((size_t)(b * NHEAD + t - 4)) * S_LEN + s] = sum + bfg[t - 4];
  }
}

// -------- per-(b,n) scan --------
__global__ __launch_bounds__(256) void scan_kernel(const float* __restrict__ igpre,
                                                   const float* __restrict__ fgpre,
                                                   float* __restrict__ a_o,
                                                   float* __restrict__ rm_o,
                                                   float* __restrict__ e_o) {
  __shared__ float sd[256];
  const int bn = blockIdx.x, t = threadIdx.x;
  const size_t base = (size_t)bn * S_LEN + t * 8;
  float cs[8];
  float run = 0.0f;
#pragma unroll
  for (int u = 0; u < 8; ++u) { run += logsigf(fgpre[base + u]); cs[u] = run; }
  sd[t] = run;
  __syncthreads();
  for (int off = 1; off < 256; off <<= 1) {
    const float vv2 = (t >= off) ? sd[t - off] : 0.0f;
    __syncthreads();
    sd[t] += vv2;
    __syncthreads();
  }
  const float exs = (t > 0) ? sd[t - 1] : 0.0f;
  __syncthreads();
  float av[8], pm[8];
  float rmax = -INFINITY;
#pragma unroll
  for (int u = 0; u < 8; ++u) {
    const float L = exs + cs[u];
    cs[u] = L;
    av[u] = igpre[base + u] - L;
    rmax = fmaxf(rmax, av[u]);
    pm[u] = rmax;
  }
  sd[t] = rmax;
  __syncthreads();
  for (int off = 1; off < 256; off <<= 1) {
    const float vv2 = (t >= off) ? sd[t - off] : -INFINITY;
    __syncthreads();
    sd[t] = fmaxf(sd[t], vv2);
    __syncthreads();
  }
  const float exm = (t > 0) ? sd[t - 1] : -INFINITY;
#pragma unroll
  for (int u = 0; u < 8; ++u) {
    const float rmv = fmaxf(exm, pm[u]);
    a_o[base + u] = av[u];
    rm_o[base + u] = rmv;
    e_o[base + u] = expf(-(cs[u] + rmv));
  }
}

// ---------------- mLSTM core: MFMA flash-style, no atomics ----------
__global__ __launch_bounds__(512) void mlstm_mfma(
    const unsigned short* __restrict__ qg, const unsigned short* __restrict__ kg,
    const unsigned short* __restrict__ vtg,
    const float* __restrict__ ag, const float* __restrict__ rmg,
    float* __restrict__ hraw, float* __restrict__ rsumg) {
  __shared__ unsigned short Ks[64 * 512];
  __shared__ unsigned short Ps[64 * 64];
  __shared__ float rsl[8][16];
  const int tid = threadIdx.x;
  const int w = tid >> 6, l = tid & 63;
  const int lm = l & 15, l4 = l >> 4;
  const int beta = blockIdx.x;
  const int bn = beta & 7;          // XCD locality for vT panel
  const int part = (beta >> 3) & 1;
  const int idx = beta >> 4;
  const int qi = (idx < 16) ? (31 - idx) : (idx - 16);  // CU-pair load balance
  const int i0 = qi << 6;
  const int b = bn >> 2, n = bn & 3;
  float* hp = hraw + (size_t)part * ((size_t)BATCH * S_LEN * INNERD);
  float* rp = rsumg + (size_t)part * ((size_t)BATCH * NHEAD * S_LEN);

  const int rA = ((w >> 1) << 4) + lm;
  short8v qf[16];
  {
    const unsigned short* qp = qg + (size_t)(b * S_LEN + i0 + rA) * INNERD + n * DHEAD + l4 * 8;
#pragma unroll
    for (int ks = 0; ks < 16; ++ks) qf[ks] = *(const short8v*)(qp + ks * 32);
  }
  const int rD = ((w >> 1) << 4) + (l4 << 2);
  float rm4[4];
#pragma unroll
  for (int r = 0; r < 4; ++r) rm4[r] = rmg[(size_t)bn * S_LEN + i0 + rD + r];
  const int cb0 = (w & 1) << 1;

  f32x4 acc[16];
#pragma unroll
  for (int i2 = 0; i2 < 16; ++i2) acc[i2] = (f32x4){0.f, 0.f, 0.f, 0.f};
  float rs4[4] = {0.f, 0.f, 0.f, 0.f};

  const int Tn = qi + 1;
  for (int jt = part; jt < Tn; jt += 2) {
    const int j0 = jt << 6;
    short8v vf[8];
#pragma unroll
    for (int db = 0; db < 4; ++db)
#pragma unroll
      for (int ks = 0; ks < 2; ++ks)
        vf[db * 2 + ks] = *(const short8v*)(vtg + (size_t)(bn * DHEAD + w * 64 + db * 16 + lm) * S_LEN + j0 + ks * 32 + l4 * 8);
    const float a0 = ag[(size_t)bn * S_LEN + j0 + cb0 * 16 + lm];
    const float a1 = ag[(size_t)bn * S_LEN + j0 + cb0 * 16 + 16 + lm];
#pragma unroll
    for (int it = 0; it < 8; ++it) {
      const int row = it * 8 + w;
      gll16((const char*)kg + ((size_t)(b * S_LEN + j0 + row) * INNERD + n * DHEAD) * 2 + ((l * 16) ^ ((row & 7) << 4)),
            (char*)Ks + row * 1024);
    }
    __syncthreads();
    f32x4 s0 = (f32x4){0.f, 0.f, 0.f, 0.f}, s1 = (f32x4){0.f, 0.f, 0.f, 0.f};
#pragma unroll
    for (int ks = 0; ks < 16; ++ks) {
      const short8v b0 = *(const short8v*)((const char*)Ks + (cb0 * 16 + lm) * 1024 + ((ks * 64 + l4 * 16) ^ ((lm & 7) << 4)));
      const short8v b1 = *(const short8v*)((const char*)Ks + ((cb0 + 1) * 16 + lm) * 1024 + ((ks * 64 + l4 * 16) ^ ((lm & 7) << 4)));
      s0 = MFMA_BF16(qf[ks], b0, s0);
      s1 = MFMA_BF16(qf[ks], b1, s1);
    }
#pragma unroll
    for (int half = 0; half < 2; ++half) {
      const f32x4 sv = half ? s1 : s0;
      const float av = half ? a1 : a0;
      const int jl = (cb0 + half) * 16 + lm;
#pragma unroll
      for (int r = 0; r < 4; ++r) {
        const int il = rD + r;
        const float es = __expf(av - rm4[r]);
        const float p = (j0 + jl <= i0 + il) ? sv[r] * SCALE_QK * es : 0.0f;
        rs4[r] += p;
        *((unsigned short*)((char*)Ps + il * 128 + ((jl * 2) ^ ((il & 7) << 4)))) = f2bf(p);
      }
    }
    __syncthreads();
#pragma unroll
    for (int ks = 0; ks < 2; ++ks) {
      short8v pa[4];
#pragma unroll
      for (int rb = 0; rb < 4; ++rb)
        pa[rb] = *(const short8v*)((const char*)Ps + (rb * 16 + lm) * 128 + ((ks * 64 + l4 * 16) ^ ((lm & 7) << 4)));
#pragma unroll
      for (int rb = 0; rb < 4; ++rb)
#pragma unroll
        for (int db = 0; db < 4; ++db)
          acc[rb * 4 + db] = MFMA_BF16(pa[rb], vf[db * 2 + ks], acc[rb * 4 + db]);
    }
    __syncthreads();
  }
  // rowsum combine via LDS (two waves share each 16-row block)
#pragma unroll
  for (int r = 0; r < 4; ++r) {
    float v2 = rs4[r];
    v2 += __shfl_xor(v2, 1, 64);
    v2 += __shfl_xor(v2, 2, 64);
    v2 += __shfl_xor(v2, 4, 64);
    v2 += __shfl_xor(v2, 8, 64);
    if (lm == 0) rsl[w][l4 * 4 + r] = v2;
  }
  __syncthreads();
  if (tid < 64) {
    const int rblk = tid >> 4, rloc = tid & 15;
    rp[(size_t)bn * S_LEN + i0 + rblk * 16 + rloc] = rsl[rblk * 2][rloc] + rsl[rblk * 2 + 1][rloc];
  }
  // raw h partial store (no atomics; zero when loop empty)
#pragma unroll
  for (int rb = 0; rb < 4; ++rb)
#pragma unroll
    for (int db = 0; db < 4; ++db) {
      float* dst = hp + (size_t)(b * S_LEN + i0 + rb * 16 + l4 * 4) * INNERD + n * DHEAD + w * 64 + db * 16 + lm;
#pragma unroll
      for (int r = 0; r < 4; ++r) dst[(size_t)r * INNERD] = acc[rb * 4 + db][r];
    }
}

// ------- mhln: merge partials + norm + LN + conv-skip + swish(z), bf16 out -------
__global__ __launch_bounds__(256) void mhln_kernel(
    const float* __restrict__ h, const unsigned short* __restrict__ xm,
    const unsigned short* __restrict__ zb,
    const float* __restrict__ cw, const float* __restrict__ cbias,
    const float* __restrict__ rsumg, const float* __restrict__ eg,
    const float* __restrict__ normw, const float* __restrict__ skip,
    unsigned short* __restrict__ hstate) {
  const int bs = blockIdx.x, t = threadIdx.x;
  const int bb = bs >> 11, s = bs & (S_LEN - 1);
  const int n = t >> 6, lane = t & 63;
  const int cp0 = n * DHEAD + lane * 8;
  const size_t hb = (size_t)bs * INNERD + cp0;
  const size_t HOFF = (size_t)BATCH * S_LEN * INNERD;
  const int bn = bb * NHEAD + n;
  const float rsv = rsumg[(size_t)bn * S_LEN + s] + rsumg[(size_t)BATCH * NHEAD * S_LEN + bn * S_LEN + s];
  const float ev = eg[(size_t)bn * S_LEN + s];
  const float inorm = 1.0f / (fmaxf(fabsf(rsv), ev) + 1e-6f);
  const float4 v0 = *(const float4*)(h + hb);
  const float4 v1 = *(const float4*)(h + hb + 4);
  const float4 u0 = *(const float4*)(h + HOFF + hb);
  const float4 u1 = *(const float4*)(h + HOFF + hb + 4);
  float vals[8] = {(v0.x + u0.x) * inorm, (v0.y + u0.y) * inorm, (v0.z + u0.z) * inorm,
                   (v0.w + u0.w) * inorm, (v1.x + u1.x) * inorm, (v1.y + u1.y) * inorm,
                   (v1.z + u1.z) * inorm, (v1.w + u1.w) * inorm};
  float sum = 0.0f;
#pragma unroll
  for (int u = 0; u < 8; ++u) sum += vals[u];
#pragma unroll
  for (int m = 32; m >= 1; m >>= 1) sum += __shfl_xor(sum, m, 64);
  const float mu = sum * (1.0f / 512.0f);
  float vs2 = 0.0f;
#pragma unroll
  for (int u = 0; u < 8; ++u) { const float d = vals[u] - mu; vs2 += d * d; }
#pragma unroll
  for (int m = 32; m >= 1; m >>= 1) vs2 += __shfl_xor(vs2, m, 64);
  const float rstd = rsqrtf(vs2 * (1.0f / 512.0f) + 1e-6f);
  float xa8[8];
  {
    float accv[8];
#pragma unroll
    for (int u = 0; u < 8; ++u) accv[u] = cbias[cp0 + u];
#pragma unroll
    for (int i2 = 0; i2 < 4; ++i2) {
      const int sj = s - 3 + i2;
      if (sj >= 0) {
        const short8v xv = *(const short8v*)(xm + (size_t)(bs - 3 + i2) * INNERD + cp0);
#pragma unroll
        for (int u = 0; u < 8; ++u)
          accv[u] += bf2f((unsigned short)xv[u]) * cw[i2 * INNERD + cp0 + u];
      }
    }
#pragma unroll
    for (int u = 0; u < 8; ++u) xa8[u] = swishf(accv[u]);
  }
  const short8v zv = *(const short8v*)(zb + (size_t)bs * INNERD + cp0);
  short8v o;
#pragma unroll
  for (int u = 0; u < 8; ++u) {
    const int cp = cp0 + u;
    const float hn = (vals[u] - mu) * rstd * normw[cp];
    const float z = bf2f((unsigned short)zv[u]);
    o[u] = (short)f2bf((hn + skip[cp] * xa8[u]) * swishf(z));
  }
  *(short8v*)(hstate + hb) = o;
}

extern "C" void kernel_launch(void* const* d_in, const int* in_sizes, int n_in,
                              void* d_out, int out_size, void* d_ws, size_t ws_size,
                              hipStream_t stream) {
  const float* x     = (const float*)d_in[0];
  const float* Wup   = (const float*)d_in[1];
  const float* cw    = (const float*)d_in[2];
  const float* cb    = (const float*)d_in[3];
  const float* Wq    = (const float*)d_in[4];
  const float* Wk    = (const float*)d_in[5];
  const float* Wv    = (const float*)d_in[6];
  const float* Wig   = (const float*)d_in[7];
  const float* big   = (const float*)d_in[8];
  const float* Wfg   = (const float*)d_in[9];
  const float* bfg   = (const float*)d_in[10];
  const float* normw = (const float*)d_in[11];
  const float* skip  = (const float*)d_in[12];
  const float* Wdown = (const float*)d_in[13];
  float* out = (float*)d_out;

  float* ws = (float*)d_ws;
  size_t off = 0;
  const size_t MR = (size_t)BATCH * S_LEN;  // 4096
  const size_t GSZ = (size_t)BATCH * NHEAD * S_LEN;  // 16384
  unsigned short* xm  = (unsigned short*)(ws + off); off += MR * INNERD / 2;
  unsigned short* zb  = (unsigned short*)(ws + off); off += MR * INNERD / 2;
  float* hraw         = ws + off;                    off += 2 * MR * INNERD;   // two partials
  unsigned short* qb  = (unsigned short*)(ws + off); off += MR * INNERD / 2;
  unsigned short* kb  = (unsigned short*)(ws + off); off += MR * INNERD / 2;
  unsigned short* vt  = (unsigned short*)(ws + off); off += MR * INNERD / 2;
  float* igpre  = ws + off; off += GSZ;
  float* fgpre  = ws + off; off += GSZ;
  float* a_buf  = ws + off; off += GSZ;
  float* rm_buf = ws + off; off += GSZ;
  float* e_buf  = ws + off; off += GSZ;
  float* rsum   = ws + off; off += 2 * GSZ;          // two partials
  unsigned short* Wpk = (unsigned short*)(ws + off); off += 12 * 256 * 8 / 2;
  float* Cg     = ws + off; off += 4 * (size_t)INNERD * 4;
  if (ws_size < off * sizeof(float)) return;

  // aliases into dead regions
  unsigned short* vb     = (unsigned short*)hraw;                       // dead before mlstm writes
  unsigned short* x_bf   = (unsigned short*)(hraw + MR * INNERD);       // part-1 region, dead before mlstm
  unsigned short* WupT   = vt;                                          // dead before trv writes vt
  unsigned short* WdT    = kb;                                          // dead after mlstm
  unsigned short* hstate = qb;                                          // dead after mlstm

  prep_kernel<<<1, 256, 0, stream>>>(Wq, Wk, Wv, Wig, Wfg, Wpk, Cg);
  cast_kernel<<<2048, 256, 0, stream>>>(x, x_bf);
  trc_kernel<<<dim3(32, 8), 256, 0, stream>>>(Wup, WupT, 1024, 4096);
  gemm_bf16<1><<<dim3(32, 32), 256, 0, stream>>>(x_bf, WupT, nullptr, xm, zb, 4096, 4096, 1024);
  headwise_kernel<<<4096, 256, 0, stream>>>(xm, Wpk, Cg, cw, cb, big, bfg,
                                            qb, kb, vb, igpre, fgpre);
  trv_kernel<<<dim3(16, 4, 8), 256, 0, stream>>>(vb, vt);
  scan_kernel<<<8, 256, 0, stream>>>(igpre, fgpre, a_buf, rm_buf, e_buf);
  mlstm_mfma<<<512, 512, 0, stream>>>(qb, kb, vt, a_buf, rm_buf, hraw, rsum);
  trc_kernel<<<dim3(8, 16), 256, 0, stream>>>(Wdown, WdT, 2048, 1024);
  mhln_kernel<<<4096, 256, 0, stream>>>(hraw, xm, zb, cw, cb, rsum, e_buf, normw, skip, hstate);
  gemm_bf16<0><<<dim3(8, 32), 256, 0, stream>>>(hstate, WdT, out, nullptr, nullptr, 4096, 1024, 2048);
}

// Round 4
// 427.693 us; speedup vs baseline: 8.5338x; 1.1879x over previous
//
#include <hip/hip_runtime.h>
#include <math.h>

#define S_LEN 2048
#define INNERD 2048
#define NHEAD 4
#define DHEAD 512
#define BATCH 2
#define SCALE_QK 0.044194173824159216f

typedef __attribute__((ext_vector_type(8))) short short8v;
typedef __attribute__((ext_vector_type(4))) float f32x4;

#define MFMA_BF16(A, B, C) __builtin_amdgcn_mfma_f32_16x16x32_bf16(A, B, C, 0, 0, 0)

__device__ __forceinline__ void gll16(const void* g, void* l) {
  __builtin_amdgcn_global_load_lds((const __attribute__((address_space(1))) unsigned int*)g,
                                   (__attribute__((address_space(3))) unsigned int*)l,
                                   16, 0, 0);
}

__device__ __forceinline__ unsigned short f2bf(float x) {
  union { float f; unsigned u; } v; v.f = x;
  unsigned r = v.u + 0x7FFFu + ((v.u >> 16) & 1u);
  return (unsigned short)(r >> 16);
}
__device__ __forceinline__ float bf2f(unsigned short x) {
  union { unsigned u; float f; } v; v.u = ((unsigned)x) << 16; return v.f;
}
__device__ __forceinline__ float swishf(float x) { return x / (1.0f + __expf(-x)); }
__device__ __forceinline__ float logsigf(float x) {
  return (x >= 0.0f) ? -log1pf(expf(-x)) : (x - log1pf(expf(x)));
}

// ---------------- cast f32 -> bf16 (8 elems/thread) ----------------
__global__ __launch_bounds__(256) void cast_kernel(const float* __restrict__ src,
                                                   unsigned short* __restrict__ dst) {
  const int i = (blockIdx.x * 256 + threadIdx.x) * 8;
  const float4 a = *(const float4*)(src + i);
  const float4 b = *(const float4*)(src + i + 4);
  short8v o;
  o[0] = (short)f2bf(a.x); o[1] = (short)f2bf(a.y); o[2] = (short)f2bf(a.z); o[3] = (short)f2bf(a.w);
  o[4] = (short)f2bf(b.x); o[5] = (short)f2bf(b.y); o[6] = (short)f2bf(b.z); o[7] = (short)f2bf(b.w);
  *(short8v*)(dst + i) = o;
}

// ------------- transpose+cast weights: f32 [R][C] -> bf16 [C][R] -------------
__global__ __launch_bounds__(256) void trc_kernel(const float* __restrict__ src,
                                                  unsigned short* __restrict__ dst,
                                                  int R, int C) {
  const int t = threadIdx.x;
  const int r0 = blockIdx.y * 128, c0 = blockIdx.x * 128;
  const int rb = (t >> 4) * 8, cb2 = (t & 15) * 8;
  float vreg[8][8];
#pragma unroll
  for (int u = 0; u < 8; ++u) {
    const float4 p0 = *(const float4*)(src + (size_t)(r0 + rb + u) * C + c0 + cb2);
    const float4 p1 = *(const float4*)(src + (size_t)(r0 + rb + u) * C + c0 + cb2 + 4);
    vreg[u][0] = p0.x; vreg[u][1] = p0.y; vreg[u][2] = p0.z; vreg[u][3] = p0.w;
    vreg[u][4] = p1.x; vreg[u][5] = p1.y; vreg[u][6] = p1.z; vreg[u][7] = p1.w;
  }
#pragma unroll
  for (int j = 0; j < 8; ++j) {
    short8v o;
#pragma unroll
    for (int u = 0; u < 8; ++u) o[u] = (short)f2bf(vreg[u][j]);
    *(short8v*)(dst + (size_t)(c0 + cb2 + j) * R + r0 + rb) = o;
  }
}

// ------------- v bf16 [4096][2048] -> vT bf16 [8][512][2048] -------------
__global__ __launch_bounds__(256) void trv_kernel(const unsigned short* __restrict__ v,
                                                  unsigned short* __restrict__ vt) {
  const int t = threadIdx.x;
  const int s0 = blockIdx.x * 128;
  const int d0 = blockIdx.y * 128;
  const int bn = blockIdx.z;
  const int b = bn >> 2, n = bn & 3;
  const int sb = (t >> 4) * 8, db = (t & 15) * 8;
  unsigned short r[8][8];
#pragma unroll
  for (int u = 0; u < 8; ++u) {
    const short8v x2 = *(const short8v*)(v + (size_t)(b * S_LEN + s0 + sb + u) * INNERD + n * DHEAD + d0 + db);
#pragma unroll
    for (int j = 0; j < 8; ++j) r[u][j] = (unsigned short)x2[j];
  }
#pragma unroll
  for (int j = 0; j < 8; ++j) {
    short8v o;
#pragma unroll
    for (int u = 0; u < 8; ++u) o[u] = (short)r[u][j];
    *(short8v*)(vt + (size_t)(bn * DHEAD + d0 + db + j) * S_LEN + s0 + sb) = o;
  }
}

// ------- prep: pack qkv weights bf16 per-thread + fold gate weights (transposed bf16) -------
// Wpk [12][256][8] bf16.  CgT bf16 [16][2048]: rows 0-3 ig-vs-xa, 4-7 ig-vs-xm,
// 8-11 fg-vs-xa, 12-15 fg-vs-xm.
__global__ __launch_bounds__(256) void prep_kernel(
    const float* __restrict__ Wq, const float* __restrict__ Wk, const float* __restrict__ Wv,
    const float* __restrict__ Wig, const float* __restrict__ Wfg,
    unsigned short* __restrict__ Wpk, unsigned short* __restrict__ CgT) {
  const int t = threadIdx.x;
  float wq[2][16], wk[2][16], wv[2][16];
#pragma unroll
  for (int hh = 0; hh < 2; ++hh) {
    const int h = 2 * t + hh;
#pragma unroll
    for (int j = 0; j < 16; ++j) {
      wq[hh][j] = Wq[(size_t)h * 16 + j];
      wk[hh][j] = Wk[(size_t)h * 16 + j];
      wv[hh][j] = Wv[(size_t)h * 16 + j];
    }
  }
#pragma unroll
  for (int hh = 0; hh < 2; ++hh)
#pragma unroll
    for (int sub = 0; sub < 2; ++sub) {
      short8v oq, ok, ov;
#pragma unroll
      for (int j = 0; j < 8; ++j) {
        oq[j] = (short)f2bf(wq[hh][sub * 8 + j]);
        ok[j] = (short)f2bf(wk[hh][sub * 8 + j]);
        ov[j] = (short)f2bf(wv[hh][sub * 8 + j]);
      }
      *(short8v*)(Wpk + ((size_t)(0 + hh * 2 + sub) * 256 + t) * 8) = oq;
      *(short8v*)(Wpk + ((size_t)(4 + hh * 2 + sub) * 256 + t) * 8) = ok;
      *(short8v*)(Wpk + ((size_t)(8 + hh * 2 + sub) * 256 + t) * 8) = ov;
    }
#pragma unroll
  for (int u = 0; u < 8; ++u) {
    const int hh = u >> 2, d = u & 3;
    const int h = 2 * t + hh;
    float cia[4] = {0, 0, 0, 0}, cim[4] = {0, 0, 0, 0};
    float cfa[4] = {0, 0, 0, 0}, cfm[4] = {0, 0, 0, 0};
#pragma unroll
    for (int o = 0; o < 4; ++o) {
      const int row = h * 4 + o;
      const float aq = wq[hh][o * 4 + d], ak = wk[hh][o * 4 + d], av = wv[hh][o * 4 + d];
#pragma unroll
      for (int g = 0; g < 4; ++g) {
        cia[g] += aq * Wig[(size_t)row * 4 + g] + ak * Wig[(size_t)(INNERD + row) * 4 + g];
        cim[g] += av * Wig[(size_t)(2 * INNERD + row) * 4 + g];
        cfa[g] += aq * Wfg[(size_t)row * 4 + g] + ak * Wfg[(size_t)(INNERD + row) * 4 + g];
        cfm[g] += av * Wfg[(size_t)(2 * INNERD + row) * 4 + g];
      }
    }
    const int c = t * 8 + u;
#pragma unroll
    for (int g = 0; g < 4; ++g) {
      CgT[(size_t)(g) * INNERD + c] = f2bf(cia[g]);
      CgT[(size_t)(4 + g) * INNERD + c] = f2bf(cim[g]);
      CgT[(size_t)(8 + g) * INNERD + c] = f2bf(cfa[g]);
      CgT[(size_t)(12 + g) * INNERD + c] = f2bf(cfm[g]);
    }
  }
}

// ---------------- bf16 MFMA GEMM: C[M,N] = A[M,K] * Bt[N,K]^T ----------------
template <int OUTMODE>
__global__ __launch_bounds__(256) void gemm_bf16(const unsigned short* __restrict__ A,
                                                 const unsigned short* __restrict__ Bt,
                                                 float* __restrict__ Cf,
                                                 unsigned short* __restrict__ Cb0,
                                                 unsigned short* __restrict__ Cb1,
                                                 int M, int N, int K) {
  __shared__ unsigned short As[128 * 64];
  __shared__ unsigned short Bs[128 * 64];
  const int tid = threadIdx.x;
  const int w = tid >> 6, l = tid & 63;
  const int lm = l & 15, l4 = l >> 4, l8 = l & 7, lr = l >> 3;
  const int nwg = gridDim.x * gridDim.y;
  int bid = blockIdx.y * gridDim.x + blockIdx.x;
  const int cpx = nwg >> 3;
  bid = (bid & 7) * cpx + (bid >> 3);  // XCD swizzle (nwg % 8 == 0)
  const int bx = bid % gridDim.x, by = bid / gridDim.x;
  const int row0 = by * 128, col0 = bx * 128;
  const int wm = w >> 1, wn = w & 1;
  f32x4 acc[16];
#pragma unroll
  for (int i2 = 0; i2 < 16; ++i2) acc[i2] = (f32x4){0.f, 0.f, 0.f, 0.f};

  const int scol = (l8 * 16) ^ (lr << 4);

  for (int k0 = 0; k0 < K; k0 += 64) {
#pragma unroll
    for (int it = 0; it < 4; ++it) {
      const int r = it * 32 + w * 8 + lr;
      gll16((const char*)A + ((size_t)(row0 + r) * K + k0) * 2 + scol,
            (char*)As + (size_t)(it * 32 + w * 8) * 128);
      gll16((const char*)Bt + ((size_t)(col0 + r) * K + k0) * 2 + scol,
            (char*)Bs + (size_t)(it * 32 + w * 8) * 128);
    }
    __syncthreads();
#pragma unroll
    for (int ks = 0; ks < 2; ++ks) {
      short8v af[4], bfr[4];
#pragma unroll
      for (int rb = 0; rb < 4; ++rb) {
        const int row = wm * 64 + rb * 16 + lm;
        af[rb] = *(const short8v*)((const char*)As + row * 128 + ((ks * 64 + l4 * 16) ^ ((lm & 7) << 4)));
      }
#pragma unroll
      for (int cb = 0; cb < 4; ++cb) {
        const int row = wn * 64 + cb * 16 + lm;
        bfr[cb] = *(const short8v*)((const char*)Bs + row * 128 + ((ks * 64 + l4 * 16) ^ ((lm & 7) << 4)));
      }
      __builtin_amdgcn_s_setprio(1);
#pragma unroll
      for (int rb = 0; rb < 4; ++rb)
#pragma unroll
        for (int cb = 0; cb < 4; ++cb)
          acc[rb * 4 + cb] = MFMA_BF16(af[rb], bfr[cb], acc[rb * 4 + cb]);
      __builtin_amdgcn_s_setprio(0);
    }
    __syncthreads();
  }
#pragma unroll
  for (int rb = 0; rb < 4; ++rb)
#pragma unroll
    for (int cb = 0; cb < 4; ++cb)
#pragma unroll
      for (int r = 0; r < 4; ++r) {
        const int gr = row0 + wm * 64 + rb * 16 + l4 * 4 + r;
        const int gc = col0 + wn * 64 + cb * 16 + lm;
        const float vv = acc[rb * 4 + cb][r];
        if (OUTMODE == 0) {
          Cf[(size_t)gr * N + gc] = vv;
        } else {
          if (gc < 2048) Cb0[(size_t)gr * 2048 + gc] = f2bf(vv);
          else Cb1[(size_t)gr * 2048 + gc - 2048] = f2bf(vv);
        }
      }
}

// ------- headwise v3: conv + swish, packed qkv proj, coalesced folded gates -------
__global__ __launch_bounds__(256) void headwise_kernel(
    const unsigned short* __restrict__ xm,
    const unsigned short* __restrict__ Wpk, const unsigned short* __restrict__ CgT,
    const float* __restrict__ cw, const float* __restrict__ cbias,
    const float* __restrict__ big, const float* __restrict__ bfg,
    unsigned short* __restrict__ q, unsigned short* __restrict__ k,
    unsigned short* __restrict__ v,
    float* __restrict__ igpre, float* __restrict__ fgpre) {
  __shared__ float red2[4][8];
  const int bs = blockIdx.x, t = threadIdx.x;
  const int s = bs & (S_LEN - 1);
  const int c0 = t * 8;
  float xa8[8], xm8[8];
  {
    float accv[8];
    const float4 cb0 = *(const float4*)(cbias + c0);
    const float4 cb1 = *(const float4*)(cbias + c0 + 4);
    accv[0] = cb0.x; accv[1] = cb0.y; accv[2] = cb0.z; accv[3] = cb0.w;
    accv[4] = cb1.x; accv[5] = cb1.y; accv[6] = cb1.z; accv[7] = cb1.w;
#pragma unroll
    for (int i = 0; i < 4; ++i) {
      if (s - 3 + i >= 0) {
        const short8v xv = *(const short8v*)(xm + (size_t)(bs - 3 + i) * INNERD + c0);
        const float4 w0 = *(const float4*)(cw + i * INNERD + c0);
        const float4 w1 = *(const float4*)(cw + i * INNERD + c0 + 4);
        const float wv2[8] = {w0.x, w0.y, w0.z, w0.w, w1.x, w1.y, w1.z, w1.w};
#pragma unroll
        for (int u = 0; u < 8; ++u) accv[u] += bf2f((unsigned short)xv[u]) * wv2[u];
      }
    }
    const short8v xs = *(const short8v*)(xm + (size_t)bs * INNERD + c0);
#pragma unroll
    for (int u = 0; u < 8; ++u) { xm8[u] = bf2f((unsigned short)xs[u]); xa8[u] = swishf(accv[u]); }
  }
  short8v qo, ko, vo;
#pragma unroll
  for (int hh = 0; hh < 2; ++hh)
#pragma unroll
    for (int sub = 0; sub < 2; ++sub) {
      const short8v wq = *(const short8v*)(Wpk + ((size_t)(0 + hh * 2 + sub) * 256 + t) * 8);
      const short8v wk = *(const short8v*)(Wpk + ((size_t)(4 + hh * 2 + sub) * 256 + t) * 8);
      const short8v wv3 = *(const short8v*)(Wpk + ((size_t)(8 + hh * 2 + sub) * 256 + t) * 8);
      float ql = 0, qh = 0, kl = 0, kh2 = 0, vl = 0, vh = 0;
#pragma unroll
      for (int d = 0; d < 4; ++d) {
        const float xa = xa8[hh * 4 + d], xv2 = xm8[hh * 4 + d];
        ql += bf2f((unsigned short)wq[d]) * xa;
        qh += bf2f((unsigned short)wq[4 + d]) * xa;
        kl += bf2f((unsigned short)wk[d]) * xa;
        kh2 += bf2f((unsigned short)wk[4 + d]) * xa;
        vl += bf2f((unsigned short)wv3[d]) * xv2;
        vh += bf2f((unsigned short)wv3[4 + d]) * xv2;
      }
      qo[hh * 4 + sub * 2] = (short)f2bf(ql); qo[hh * 4 + sub * 2 + 1] = (short)f2bf(qh);
      ko[hh * 4 + sub * 2] = (short)f2bf(kl); ko[hh * 4 + sub * 2 + 1] = (short)f2bf(kh2);
      vo[hh * 4 + sub * 2] = (short)f2bf(vl); vo[hh * 4 + sub * 2 + 1] = (short)f2bf(vh);
    }
  *(short8v*)(q + (size_t)bs * INNERD + c0) = qo;
  *(short8v*)(k + (size_t)bs * INNERD + c0) = ko;
  *(short8v*)(v + (size_t)bs * INNERD + c0) = vo;
  // gate partials: coalesced CgT rows
  float r8[8];
#pragma unroll
  for (int j = 0; j < 4; ++j) {
    const short8v ca = *(const short8v*)(CgT + (size_t)j * INNERD + c0);
    const short8v cm = *(const short8v*)(CgT + (size_t)(4 + j) * INNERD + c0);
    const short8v fa = *(const short8v*)(CgT + (size_t)(8 + j) * INNERD + c0);
    const short8v fm = *(const short8v*)(CgT + (size_t)(12 + j) * INNERD + c0);
    float si = 0.f, sf = 0.f;
#pragma unroll
    for (int u = 0; u < 8; ++u) {
      si += xa8[u] * bf2f((unsigned short)ca[u]) + xm8[u] * bf2f((unsigned short)cm[u]);
      sf += xa8[u] * bf2f((unsigned short)fa[u]) + xm8[u] * bf2f((unsigned short)fm[u]);
    }
    r8[j] = si; r8[4 + j] = sf;
  }
  // halving butterfly: 8 values over 64 lanes in 10 shuffles
  const int l = t & 63;
  const bool b1 = (l & 1), b2 = (l & 2), b4 = (l & 4);
  float t4[4];
#pragma unroll
  for (int i = 0; i < 4; ++i) {
    const float send = b1 ? r8[i] : r8[i + 4];
    const float recv = __shfl_xor(send, 1, 64);
    t4[i] = (b1 ? r8[i + 4] : r8[i]) + recv;
  }
  float u2[2];
#pragma unroll
  for (int i = 0; i < 2; ++i) {
    const float send = b2 ? t4[i] : t4[i + 2];
    const float recv = __shfl_xor(send, 2, 64);
    u2[i] = (b2 ? t4[i + 2] : t4[i]) + recv;
  }
  float wsum;
  {
    const float send = b4 ? u2[0] : u2[1];
    const float recv = __shfl_xor(send, 4, 64);
    wsum = (b4 ? u2[1] : u2[0]) + recv;
  }
  wsum += __shfl_xor(wsum, 8, 64);
  wsum += __shfl_xor(wsum, 16, 64);
  wsum += __shfl_xor(wsum, 32, 64);
  if (l < 8) {
    const int perm = ((l & 1) << 2) | (l & 2) | ((l >> 2) & 1);
    red2[t >> 6][perm] = wsum;
  }
  __syncthreads();
  if (t < 8) {
    const float sum = red2[0][t] + red2[1][t] + red2[2][t] + red2[3][t];
    const int b = bs >> 11;
    if (t < 4) igpre[((size_t)(b * NHEAD + t)) * S_LEN + s] = sum + big[t];
    else fgpre[((size_t)(b * NHEAD + t - 4)) * S_LEN + s] = sum + bfg[t - 4];
  }
}

// -------- per-(b,n) scan --------
__global__ __launch_bounds__(256) void scan_kernel(const float* __restrict__ igpre,
                                                   const float* __restrict__ fgpre,
                                                   float* __restrict__ a_o,
                                                   float* __restrict__ rm_o,
                                                   float* __restrict__ e_o) {
  __shared__ float sd[256];
  const int bn = blockIdx.x, t = threadIdx.x;
  const size_t base = (size_t)bn * S_LEN + t * 8;
  float cs[8];
  float run = 0.0f;
#pragma unroll
  for (int u = 0; u < 8; ++u) { run += logsigf(fgpre[base + u]); cs[u] = run; }
  sd[t] = run;
  __syncthreads();
  for (int off = 1; off < 256; off <<= 1) {
    const float vv2 = (t >= off) ? sd[t - off] : 0.0f;
    __syncthreads();
    sd[t] += vv2;
    __syncthreads();
  }
  const float exs = (t > 0) ? sd[t - 1] : 0.0f;
  __syncthreads();
  float av[8], pm[8];
  float rmax = -INFINITY;
#pragma unroll
  for (int u = 0; u < 8; ++u) {
    const float L = exs + cs[u];
    cs[u] = L;
    av[u] = igpre[base + u] - L;
    rmax = fmaxf(rmax, av[u]);
    pm[u] = rmax;
  }
  sd[t] = rmax;
  __syncthreads();
  for (int off = 1; off < 256; off <<= 1) {
    const float vv2 = (t >= off) ? sd[t - off] : -INFINITY;
    __syncthreads();
    sd[t] = fmaxf(sd[t], vv2);
    __syncthreads();
  }
  const float exm = (t > 0) ? sd[t - 1] : -INFINITY;
#pragma unroll
  for (int u = 0; u < 8; ++u) {
    const float rmv = fmaxf(exm, pm[u]);
    a_o[base + u] = av[u];
    rm_o[base + u] = rmv;
    e_o[base + u] = expf(-(cs[u] + rmv));
  }
}

// ---------------- mLSTM core: MFMA flash-style, no atomics ----------
__global__ __launch_bounds__(512) void mlstm_mfma(
    const unsigned short* __restrict__ qg, const unsigned short* __restrict__ kg,
    const unsigned short* __restrict__ vtg,
    const float* __restrict__ ag, const float* __restrict__ rmg,
    float* __restrict__ hraw, float* __restrict__ rsumg) {
  __shared__ unsigned short Ks[64 * 512];
  __shared__ unsigned short Ps[64 * 64];
  __shared__ float rsl[8][16];
  const int tid = threadIdx.x;
  const int w = tid >> 6, l = tid & 63;
  const int lm = l & 15, l4 = l >> 4;
  const int beta = blockIdx.x;
  const int bn = beta & 7;          // XCD locality for vT panel
  const int part = (beta >> 3) & 1;
  const int idx = beta >> 4;
  const int qi = (idx < 16) ? (31 - idx) : (idx - 16);  // heavy blocks first
  const int i0 = qi << 6;
  const int b = bn >> 2, n = bn & 3;
  float* hp = hraw + (size_t)part * ((size_t)BATCH * S_LEN * INNERD);
  float* rp = rsumg + (size_t)part * ((size_t)BATCH * NHEAD * S_LEN);

  const int rA = ((w >> 1) << 4) + lm;
  short8v qf[16];
  {
    const unsigned short* qp = qg + (size_t)(b * S_LEN + i0 + rA) * INNERD + n * DHEAD + l4 * 8;
#pragma unroll
    for (int ks = 0; ks < 16; ++ks) qf[ks] = *(const short8v*)(qp + ks * 32);
  }
  const int rD = ((w >> 1) << 4) + (l4 << 2);
  float rm4[4];
#pragma unroll
  for (int r = 0; r < 4; ++r) rm4[r] = rmg[(size_t)bn * S_LEN + i0 + rD + r];
  const int cb0 = (w & 1) << 1;

  f32x4 acc[16];
#pragma unroll
  for (int i2 = 0; i2 < 16; ++i2) acc[i2] = (f32x4){0.f, 0.f, 0.f, 0.f};
  float rs4[4] = {0.f, 0.f, 0.f, 0.f};

  const int Tn = qi + 1;
  for (int jt = part; jt < Tn; jt += 2) {
    const int j0 = jt << 6;
    short8v vf[8];
#pragma unroll
    for (int db = 0; db < 4; ++db)
#pragma unroll
      for (int ks = 0; ks < 2; ++ks)
        vf[db * 2 + ks] = *(const short8v*)(vtg + (size_t)(bn * DHEAD + w * 64 + db * 16 + lm) * S_LEN + j0 + ks * 32 + l4 * 8);
    const float a0 = ag[(size_t)bn * S_LEN + j0 + cb0 * 16 + lm];
    const float a1 = ag[(size_t)bn * S_LEN + j0 + cb0 * 16 + 16 + lm];
#pragma unroll
    for (int it = 0; it < 8; ++it) {
      const int row = it * 8 + w;
      gll16((const char*)kg + ((size_t)(b * S_LEN + j0 + row) * INNERD + n * DHEAD) * 2 + ((l * 16) ^ ((row & 7) << 4)),
            (char*)Ks + row * 1024);
    }
    __syncthreads();
    f32x4 s0 = (f32x4){0.f, 0.f, 0.f, 0.f}, s1 = (f32x4){0.f, 0.f, 0.f, 0.f};
    __builtin_amdgcn_s_setprio(1);
#pragma unroll
    for (int ks = 0; ks < 16; ++ks) {
      const short8v b0 = *(const short8v*)((const char*)Ks + (cb0 * 16 + lm) * 1024 + ((ks * 64 + l4 * 16) ^ ((lm & 7) << 4)));
      const short8v b1 = *(const short8v*)((const char*)Ks + ((cb0 + 1) * 16 + lm) * 1024 + ((ks * 64 + l4 * 16) ^ ((lm & 7) << 4)));
      s0 = MFMA_BF16(qf[ks], b0, s0);
      s1 = MFMA_BF16(qf[ks], b1, s1);
    }
    __builtin_amdgcn_s_setprio(0);
#pragma unroll
    for (int half = 0; half < 2; ++half) {
      const f32x4 sv = half ? s1 : s0;
      const float av = half ? a1 : a0;
      const int jl = (cb0 + half) * 16 + lm;
#pragma unroll
      for (int r = 0; r < 4; ++r) {
        const int il = rD + r;
        const float es = __expf(av - rm4[r]);
        const float p = (j0 + jl <= i0 + il) ? sv[r] * SCALE_QK * es : 0.0f;
        rs4[r] += p;
        *((unsigned short*)((char*)Ps + il * 128 + ((jl * 2) ^ ((il & 7) << 4)))) = f2bf(p);
      }
    }
    __syncthreads();
#pragma unroll
    for (int ks = 0; ks < 2; ++ks) {
      short8v pa[4];
#pragma unroll
      for (int rb = 0; rb < 4; ++rb)
        pa[rb] = *(const short8v*)((const char*)Ps + (rb * 16 + lm) * 128 + ((ks * 64 + l4 * 16) ^ ((lm & 7) << 4)));
      __builtin_amdgcn_s_setprio(1);
#pragma unroll
      for (int rb = 0; rb < 4; ++rb)
#pragma unroll
        for (int db = 0; db < 4; ++db)
          acc[rb * 4 + db] = MFMA_BF16(pa[rb], vf[db * 2 + ks], acc[rb * 4 + db]);
      __builtin_amdgcn_s_setprio(0);
    }
    __syncthreads();
  }
  // rowsum combine via LDS (two waves share each 16-row block)
#pragma unroll
  for (int r = 0; r < 4; ++r) {
    float v2 = rs4[r];
    v2 += __shfl_xor(v2, 1, 64);
    v2 += __shfl_xor(v2, 2, 64);
    v2 += __shfl_xor(v2, 4, 64);
    v2 += __shfl_xor(v2, 8, 64);
    if (lm == 0) rsl[w][l4 * 4 + r] = v2;
  }
  __syncthreads();
  if (tid < 64) {
    const int rblk = tid >> 4, rloc = tid & 15;
    rp[(size_t)bn * S_LEN + i0 + rblk * 16 + rloc] = rsl[rblk * 2][rloc] + rsl[rblk * 2 + 1][rloc];
  }
  // raw h partial store (no atomics; zero when loop empty)
#pragma unroll
  for (int rb = 0; rb < 4; ++rb)
#pragma unroll
    for (int db = 0; db < 4; ++db) {
      float* dst = hp + (size_t)(b * S_LEN + i0 + rb * 16 + l4 * 4) * INNERD + n * DHEAD + w * 64 + db * 16 + lm;
#pragma unroll
      for (int r = 0; r < 4; ++r) dst[(size_t)r * INNERD] = acc[rb * 4 + db][r];
    }
}

// ------- mhln: merge partials + norm + LN + conv-skip + swish(z), bf16 out -------
__global__ __launch_bounds__(256) void mhln_kernel(
    const float* __restrict__ h, const unsigned short* __restrict__ xm,
    const unsigned short* __restrict__ zb,
    const float* __restrict__ cw, const float* __restrict__ cbias,
    const float* __restrict__ rsumg, const float* __restrict__ eg,
    const float* __restrict__ normw, const float* __restrict__ skip,
    unsigned short* __restrict__ hstate) {
  const int bs = blockIdx.x, t = threadIdx.x;
  const int bb = bs >> 11, s = bs & (S_LEN - 1);
  const int n = t >> 6, lane = t & 63;
  const int cp0 = n * DHEAD + lane * 8;
  const size_t hb = (size_t)bs * INNERD + cp0;
  const size_t HOFF = (size_t)BATCH * S_LEN * INNERD;
  const int bn = bb * NHEAD + n;
  const float rsv = rsumg[(size_t)bn * S_LEN + s] + rsumg[(size_t)BATCH * NHEAD * S_LEN + bn * S_LEN + s];
  const float ev = eg[(size_t)bn * S_LEN + s];
  const float inorm = 1.0f / (fmaxf(fabsf(rsv), ev) + 1e-6f);
  const float4 v0 = *(const float4*)(h + hb);
  const float4 v1 = *(const float4*)(h + hb + 4);
  const float4 u0 = *(const float4*)(h + HOFF + hb);
  const float4 u1 = *(const float4*)(h + HOFF + hb + 4);
  float vals[8] = {(v0.x + u0.x) * inorm, (v0.y + u0.y) * inorm, (v0.z + u0.z) * inorm,
                   (v0.w + u0.w) * inorm, (v1.x + u1.x) * inorm, (v1.y + u1.y) * inorm,
                   (v1.z + u1.z) * inorm, (v1.w + u1.w) * inorm};
  float sum = 0.0f;
#pragma unroll
  for (int u = 0; u < 8; ++u) sum += vals[u];
#pragma unroll
  for (int m = 32; m >= 1; m >>= 1) sum += __shfl_xor(sum, m, 64);
  const float mu = sum * (1.0f / 512.0f);
  float vs2 = 0.0f;
#pragma unroll
  for (int u = 0; u < 8; ++u) { const float d = vals[u] - mu; vs2 += d * d; }
#pragma unroll
  for (int m = 32; m >= 1; m >>= 1) vs2 += __shfl_xor(vs2, m, 64);
  const float rstd = rsqrtf(vs2 * (1.0f / 512.0f) + 1e-6f);
  float xa8[8];
  {
    float accv[8];
#pragma unroll
    for (int u = 0; u < 8; ++u) accv[u] = cbias[cp0 + u];
#pragma unroll
    for (int i2 = 0; i2 < 4; ++i2) {
      const int sj = s - 3 + i2;
      if (sj >= 0) {
        const short8v xv = *(const short8v*)(xm + (size_t)(bs - 3 + i2) * INNERD + cp0);
#pragma unroll
        for (int u = 0; u < 8; ++u)
          accv[u] += bf2f((unsigned short)xv[u]) * cw[i2 * INNERD + cp0 + u];
      }
    }
#pragma unroll
    for (int u = 0; u < 8; ++u) xa8[u] = swishf(accv[u]);
  }
  const short8v zv = *(const short8v*)(zb + (size_t)bs * INNERD + cp0);
  short8v o;
#pragma unroll
  for (int u = 0; u < 8; ++u) {
    const int cp = cp0 + u;
    const float hn = (vals[u] - mu) * rstd * normw[cp];
    const float z = bf2f((unsigned short)zv[u]);
    o[u] = (short)f2bf((hn + skip[cp] * xa8[u]) * swishf(z));
  }
  *(short8v*)(hstate + hb) = o;
}

extern "C" void kernel_launch(void* const* d_in, const int* in_sizes, int n_in,
                              void* d_out, int out_size, void* d_ws, size_t ws_size,
                              hipStream_t stream) {
  const float* x     = (const float*)d_in[0];
  const float* Wup   = (const float*)d_in[1];
  const float* cw    = (const float*)d_in[2];
  const float* cb    = (const float*)d_in[3];
  const float* Wq    = (const float*)d_in[4];
  const float* Wk    = (const float*)d_in[5];
  const float* Wv    = (const float*)d_in[6];
  const float* Wig   = (const float*)d_in[7];
  const float* big   = (const float*)d_in[8];
  const float* Wfg   = (const float*)d_in[9];
  const float* bfg   = (const float*)d_in[10];
  const float* normw = (const float*)d_in[11];
  const float* skip  = (const float*)d_in[12];
  const float* Wdown = (const float*)d_in[13];
  float* out = (float*)d_out;

  float* ws = (float*)d_ws;
  size_t off = 0;
  const size_t MR = (size_t)BATCH * S_LEN;  // 4096
  const size_t GSZ = (size_t)BATCH * NHEAD * S_LEN;  // 16384
  unsigned short* xm  = (unsigned short*)(ws + off); off += MR * INNERD / 2;
  unsigned short* zb  = (unsigned short*)(ws + off); off += MR * INNERD / 2;
  float* hraw         = ws + off;                    off += 2 * MR * INNERD;   // two partials
  unsigned short* qb  = (unsigned short*)(ws + off); off += MR * INNERD / 2;
  unsigned short* kb  = (unsigned short*)(ws + off); off += MR * INNERD / 2;
  unsigned short* vt  = (unsigned short*)(ws + off); off += MR * INNERD / 2;
  float* igpre  = ws + off; off += GSZ;
  float* fgpre  = ws + off; off += GSZ;
  float* a_buf  = ws + off; off += GSZ;
  float* rm_buf = ws + off; off += GSZ;
  float* e_buf  = ws + off; off += GSZ;
  float* rsum   = ws + off; off += 2 * GSZ;          // two partials
  unsigned short* Wpk = (unsigned short*)(ws + off); off += 12 * 256 * 8 / 2;
  unsigned short* CgT = (unsigned short*)(ws + off); off += 16 * (size_t)INNERD / 2;
  if (ws_size < off * sizeof(float)) return;

  // aliases into dead regions
  unsigned short* vb     = (unsigned short*)hraw;                       // dead before mlstm writes
  unsigned short* x_bf   = (unsigned short*)(hraw + MR * INNERD);       // part-1 region, dead before mlstm
  unsigned short* WupT   = vt;                                          // dead before trv writes vt
  unsigned short* WdT    = kb;                                          // dead after mlstm
  unsigned short* hstate = qb;                                          // dead after mlstm

  prep_kernel<<<1, 256, 0, stream>>>(Wq, Wk, Wv, Wig, Wfg, Wpk, CgT);
  cast_kernel<<<2048, 256, 0, stream>>>(x, x_bf);
  trc_kernel<<<dim3(32, 8), 256, 0, stream>>>(Wup, WupT, 1024, 4096);
  gemm_bf16<1><<<dim3(32, 32), 256, 0, stream>>>(x_bf, WupT, nullptr, xm, zb, 4096, 4096, 1024);
  headwise_kernel<<<4096, 256, 0, stream>>>(xm, Wpk, CgT, cw, cb, big, bfg,
                                            qb, kb, vb, igpre, fgpre);
  trv_kernel<<<dim3(16, 4, 8), 256, 0, stream>>>(vb, vt);
  scan_kernel<<<8, 256, 0, stream>>>(igpre, fgpre, a_buf, rm_buf, e_buf);
  mlstm_mfma<<<512, 512, 0, stream>>>(qb, kb, vt, a_buf, rm_buf, hraw, rsum);
  trc_kernel<<<dim3(8, 16), 256, 0, stream>>>(Wdown, WdT, 2048, 1024);
  mhln_kernel<<<4096, 256, 0, stream>>>(hraw, xm, zb, cw, cb, rsum, e_buf, normw, skip, hstate);
  gemm_bf16<0><<<dim3(8, 32), 256, 0, stream>>>(hstate, WdT, out, nullptr, nullptr, 4096, 1024, 2048);
}

// Round 5
// 396.170 us; speedup vs baseline: 9.2128x; 1.0796x over previous
//
#include <hip/hip_runtime.h>
#include <math.h>

#define S_LEN 2048
#define INNERD 2048
#define NHEAD 4
#define DHEAD 512
#define BATCH 2
#define SCALE_QK 0.044194173824159216f

typedef __attribute__((ext_vector_type(8))) short short8v;
typedef __attribute__((ext_vector_type(4))) float f32x4;

#define MFMA_BF16(A, B, C) __builtin_amdgcn_mfma_f32_16x16x32_bf16(A, B, C, 0, 0, 0)

__device__ __forceinline__ void gll16(const void* g, void* l) {
  __builtin_amdgcn_global_load_lds((const __attribute__((address_space(1))) unsigned int*)g,
                                   (__attribute__((address_space(3))) unsigned int*)l,
                                   16, 0, 0);
}

__device__ __forceinline__ unsigned short f2bf(float x) {
  union { float f; unsigned u; } v; v.f = x;
  unsigned r = v.u + 0x7FFFu + ((v.u >> 16) & 1u);
  return (unsigned short)(r >> 16);
}
__device__ __forceinline__ float bf2f(unsigned short x) {
  union { unsigned u; float f; } v; v.u = ((unsigned)x) << 16; return v.f;
}
__device__ __forceinline__ float swishf(float x) { return x / (1.0f + __expf(-x)); }
__device__ __forceinline__ float logsigf(float x) {
  return (x >= 0.0f) ? -log1pf(expf(-x)) : (x - log1pf(expf(x)));
}

// ---------------- cast f32 -> bf16 (8 elems/thread) ----------------
__global__ __launch_bounds__(256) void cast_kernel(const float* __restrict__ src,
                                                   unsigned short* __restrict__ dst) {
  const int i = (blockIdx.x * 256 + threadIdx.x) * 8;
  const float4 a = *(const float4*)(src + i);
  const float4 b = *(const float4*)(src + i + 4);
  short8v o;
  o[0] = (short)f2bf(a.x); o[1] = (short)f2bf(a.y); o[2] = (short)f2bf(a.z); o[3] = (short)f2bf(a.w);
  o[4] = (short)f2bf(b.x); o[5] = (short)f2bf(b.y); o[6] = (short)f2bf(b.z); o[7] = (short)f2bf(b.w);
  *(short8v*)(dst + i) = o;
}

// ------------- transpose+cast weights: f32 [R][C] -> bf16 [C][R] -------------
__global__ __launch_bounds__(256) void trc_kernel(const float* __restrict__ src,
                                                  unsigned short* __restrict__ dst,
                                                  int R, int C) {
  const int t = threadIdx.x;
  const int r0 = blockIdx.y * 128, c0 = blockIdx.x * 128;
  const int rb = (t >> 4) * 8, cb2 = (t & 15) * 8;
  float vreg[8][8];
#pragma unroll
  for (int u = 0; u < 8; ++u) {
    const float4 p0 = *(const float4*)(src + (size_t)(r0 + rb + u) * C + c0 + cb2);
    const float4 p1 = *(const float4*)(src + (size_t)(r0 + rb + u) * C + c0 + cb2 + 4);
    vreg[u][0] = p0.x; vreg[u][1] = p0.y; vreg[u][2] = p0.z; vreg[u][3] = p0.w;
    vreg[u][4] = p1.x; vreg[u][5] = p1.y; vreg[u][6] = p1.z; vreg[u][7] = p1.w;
  }
#pragma unroll
  for (int j = 0; j < 8; ++j) {
    short8v o;
#pragma unroll
    for (int u = 0; u < 8; ++u) o[u] = (short)f2bf(vreg[u][j]);
    *(short8v*)(dst + (size_t)(c0 + cb2 + j) * R + r0 + rb) = o;
  }
}

// ------------- v bf16 [4096][2048] -> vT bf16 [8][512][2048] -------------
__global__ __launch_bounds__(256) void trv_kernel(const unsigned short* __restrict__ v,
                                                  unsigned short* __restrict__ vt) {
  const int t = threadIdx.x;
  const int s0 = blockIdx.x * 128;
  const int d0 = blockIdx.y * 128;
  const int bn = blockIdx.z;
  const int b = bn >> 2, n = bn & 3;
  const int sb = (t >> 4) * 8, db = (t & 15) * 8;
  unsigned short r[8][8];
#pragma unroll
  for (int u = 0; u < 8; ++u) {
    const short8v x2 = *(const short8v*)(v + (size_t)(b * S_LEN + s0 + sb + u) * INNERD + n * DHEAD + d0 + db);
#pragma unroll
    for (int j = 0; j < 8; ++j) r[u][j] = (unsigned short)x2[j];
  }
#pragma unroll
  for (int j = 0; j < 8; ++j) {
    short8v o;
#pragma unroll
    for (int u = 0; u < 8; ++u) o[u] = (short)r[u][j];
    *(short8v*)(vt + (size_t)(bn * DHEAD + d0 + db + j) * S_LEN + s0 + sb) = o;
  }
}

// ------- prep: pack qkv weights bf16 per-thread + fold gate weights (transposed bf16) -------
__global__ __launch_bounds__(256) void prep_kernel(
    const float* __restrict__ Wq, const float* __restrict__ Wk, const float* __restrict__ Wv,
    const float* __restrict__ Wig, const float* __restrict__ Wfg,
    unsigned short* __restrict__ Wpk, unsigned short* __restrict__ CgT) {
  const int t = threadIdx.x;
  float wq[2][16], wk[2][16], wv[2][16];
#pragma unroll
  for (int hh = 0; hh < 2; ++hh) {
    const int h = 2 * t + hh;
#pragma unroll
    for (int j = 0; j < 16; ++j) {
      wq[hh][j] = Wq[(size_t)h * 16 + j];
      wk[hh][j] = Wk[(size_t)h * 16 + j];
      wv[hh][j] = Wv[(size_t)h * 16 + j];
    }
  }
#pragma unroll
  for (int hh = 0; hh < 2; ++hh)
#pragma unroll
    for (int sub = 0; sub < 2; ++sub) {
      short8v oq, ok, ov;
#pragma unroll
      for (int j = 0; j < 8; ++j) {
        oq[j] = (short)f2bf(wq[hh][sub * 8 + j]);
        ok[j] = (short)f2bf(wk[hh][sub * 8 + j]);
        ov[j] = (short)f2bf(wv[hh][sub * 8 + j]);
      }
      *(short8v*)(Wpk + ((size_t)(0 + hh * 2 + sub) * 256 + t) * 8) = oq;
      *(short8v*)(Wpk + ((size_t)(4 + hh * 2 + sub) * 256 + t) * 8) = ok;
      *(short8v*)(Wpk + ((size_t)(8 + hh * 2 + sub) * 256 + t) * 8) = ov;
    }
#pragma unroll
  for (int u = 0; u < 8; ++u) {
    const int hh = u >> 2, d = u & 3;
    const int h = 2 * t + hh;
    float cia[4] = {0, 0, 0, 0}, cim[4] = {0, 0, 0, 0};
    float cfa[4] = {0, 0, 0, 0}, cfm[4] = {0, 0, 0, 0};
#pragma unroll
    for (int o = 0; o < 4; ++o) {
      const int row = h * 4 + o;
      const float aq = wq[hh][o * 4 + d], ak = wk[hh][o * 4 + d], av = wv[hh][o * 4 + d];
#pragma unroll
      for (int g = 0; g < 4; ++g) {
        cia[g] += aq * Wig[(size_t)row * 4 + g] + ak * Wig[(size_t)(INNERD + row) * 4 + g];
        cim[g] += av * Wig[(size_t)(2 * INNERD + row) * 4 + g];
        cfa[g] += aq * Wfg[(size_t)row * 4 + g] + ak * Wfg[(size_t)(INNERD + row) * 4 + g];
        cfm[g] += av * Wfg[(size_t)(2 * INNERD + row) * 4 + g];
      }
    }
    const int c = t * 8 + u;
#pragma unroll
    for (int g = 0; g < 4; ++g) {
      CgT[(size_t)(g) * INNERD + c] = f2bf(cia[g]);
      CgT[(size_t)(4 + g) * INNERD + c] = f2bf(cim[g]);
      CgT[(size_t)(8 + g) * INNERD + c] = f2bf(cfa[g]);
      CgT[(size_t)(12 + g) * INNERD + c] = f2bf(cfm[g]);
    }
  }
}

// ---------------- bf16 MFMA GEMM: C[M,N] = A[M,K] * Bt[N,K]^T, tile 128xBN ----------------
template <int BN, int OUTMODE>
__global__ __launch_bounds__(256) void gemm_bf16(const unsigned short* __restrict__ A,
                                                 const unsigned short* __restrict__ Bt,
                                                 float* __restrict__ Cf,
                                                 unsigned short* __restrict__ Cb0,
                                                 unsigned short* __restrict__ Cb1,
                                                 int M, int N, int K) {
  constexpr int CB = BN / 32;
  __shared__ unsigned short As[128 * 64];
  __shared__ unsigned short Bs[BN * 64];
  const int tid = threadIdx.x;
  const int w = tid >> 6, l = tid & 63;
  const int lm = l & 15, l4 = l >> 4, l8 = l & 7, lr = l >> 3;
  const int nwg = gridDim.x * gridDim.y;
  int bid = blockIdx.y * gridDim.x + blockIdx.x;
  const int cpx = nwg >> 3;
  bid = (bid & 7) * cpx + (bid >> 3);  // XCD swizzle (nwg % 8 == 0)
  const int bx = bid % gridDim.x, by = bid / gridDim.x;
  const int row0 = by * 128, col0 = bx * BN;
  const int wm = w >> 1, wn = w & 1;
  f32x4 acc[4 * CB];
#pragma unroll
  for (int i2 = 0; i2 < 4 * CB; ++i2) acc[i2] = (f32x4){0.f, 0.f, 0.f, 0.f};

  const int scol = (l8 * 16) ^ (lr << 4);

  for (int k0 = 0; k0 < K; k0 += 64) {
#pragma unroll
    for (int it = 0; it < 4; ++it) {
      const int r = it * 32 + w * 8 + lr;
      gll16((const char*)A + ((size_t)(row0 + r) * K + k0) * 2 + scol,
            (char*)As + (size_t)(it * 32 + w * 8) * 128);
    }
#pragma unroll
    for (int it = 0; it < BN / 32; ++it) {
      const int r = it * 32 + w * 8 + lr;
      gll16((const char*)Bt + ((size_t)(col0 + r) * K + k0) * 2 + scol,
            (char*)Bs + (size_t)(it * 32 + w * 8) * 128);
    }
    __syncthreads();
#pragma unroll
    for (int ks = 0; ks < 2; ++ks) {
      short8v af[4], bfr[CB];
#pragma unroll
      for (int rb = 0; rb < 4; ++rb) {
        const int row = wm * 64 + rb * 16 + lm;
        af[rb] = *(const short8v*)((const char*)As + row * 128 + ((ks * 64 + l4 * 16) ^ ((lm & 7) << 4)));
      }
#pragma unroll
      for (int cb = 0; cb < CB; ++cb) {
        const int row = wn * (BN / 2) + cb * 16 + lm;
        bfr[cb] = *(const short8v*)((const char*)Bs + row * 128 + ((ks * 64 + l4 * 16) ^ ((lm & 7) << 4)));
      }
      __builtin_amdgcn_s_setprio(1);
#pragma unroll
      for (int rb = 0; rb < 4; ++rb)
#pragma unroll
        for (int cb = 0; cb < CB; ++cb)
          acc[rb * CB + cb] = MFMA_BF16(af[rb], bfr[cb], acc[rb * CB + cb]);
      __builtin_amdgcn_s_setprio(0);
    }
    __syncthreads();
  }
#pragma unroll
  for (int rb = 0; rb < 4; ++rb)
#pragma unroll
    for (int cb = 0; cb < CB; ++cb)
#pragma unroll
      for (int r = 0; r < 4; ++r) {
        const int gr = row0 + wm * 64 + rb * 16 + l4 * 4 + r;
        const int gc = col0 + wn * (BN / 2) + cb * 16 + lm;
        const float vv = acc[rb * CB + cb][r];
        if (OUTMODE == 0) {
          Cf[(size_t)gr * N + gc] = vv;
        } else {
          if (gc < 2048) Cb0[(size_t)gr * 2048 + gc] = f2bf(vv);
          else Cb1[(size_t)gr * 2048 + gc - 2048] = f2bf(vv);
        }
      }
}

// ------- headwise: conv + swish, packed qkv proj, coalesced folded gates -------
__global__ __launch_bounds__(256) void headwise_kernel(
    const unsigned short* __restrict__ xm,
    const unsigned short* __restrict__ Wpk, const unsigned short* __restrict__ CgT,
    const float* __restrict__ cw, const float* __restrict__ cbias,
    const float* __restrict__ big, const float* __restrict__ bfg,
    unsigned short* __restrict__ q, unsigned short* __restrict__ k,
    unsigned short* __restrict__ v,
    float* __restrict__ igpre, float* __restrict__ fgpre) {
  __shared__ float red2[4][8];
  const int bs = blockIdx.x, t = threadIdx.x;
  const int s = bs & (S_LEN - 1);
  const int c0 = t * 8;
  float xa8[8], xm8[8];
  {
    float accv[8];
    const float4 cb0 = *(const float4*)(cbias + c0);
    const float4 cb1 = *(const float4*)(cbias + c0 + 4);
    accv[0] = cb0.x; accv[1] = cb0.y; accv[2] = cb0.z; accv[3] = cb0.w;
    accv[4] = cb1.x; accv[5] = cb1.y; accv[6] = cb1.z; accv[7] = cb1.w;
#pragma unroll
    for (int i = 0; i < 4; ++i) {
      if (s - 3 + i >= 0) {
        const short8v xv = *(const short8v*)(xm + (size_t)(bs - 3 + i) * INNERD + c0);
        const float4 w0 = *(const float4*)(cw + i * INNERD + c0);
        const float4 w1 = *(const float4*)(cw + i * INNERD + c0 + 4);
        const float wv2[8] = {w0.x, w0.y, w0.z, w0.w, w1.x, w1.y, w1.z, w1.w};
#pragma unroll
        for (int u = 0; u < 8; ++u) accv[u] += bf2f((unsigned short)xv[u]) * wv2[u];
      }
    }
    const short8v xs = *(const short8v*)(xm + (size_t)bs * INNERD + c0);
#pragma unroll
    for (int u = 0; u < 8; ++u) { xm8[u] = bf2f((unsigned short)xs[u]); xa8[u] = swishf(accv[u]); }
  }
  short8v qo, ko, vo;
#pragma unroll
  for (int hh = 0; hh < 2; ++hh)
#pragma unroll
    for (int sub = 0; sub < 2; ++sub) {
      const short8v wq = *(const short8v*)(Wpk + ((size_t)(0 + hh * 2 + sub) * 256 + t) * 8);
      const short8v wk = *(const short8v*)(Wpk + ((size_t)(4 + hh * 2 + sub) * 256 + t) * 8);
      const short8v wv3 = *(const short8v*)(Wpk + ((size_t)(8 + hh * 2 + sub) * 256 + t) * 8);
      float ql = 0, qh = 0, kl = 0, kh2 = 0, vl = 0, vh = 0;
#pragma unroll
      for (int d = 0; d < 4; ++d) {
        const float xa = xa8[hh * 4 + d], xv2 = xm8[hh * 4 + d];
        ql += bf2f((unsigned short)wq[d]) * xa;
        qh += bf2f((unsigned short)wq[4 + d]) * xa;
        kl += bf2f((unsigned short)wk[d]) * xa;
        kh2 += bf2f((unsigned short)wk[4 + d]) * xa;
        vl += bf2f((unsigned short)wv3[d]) * xv2;
        vh += bf2f((unsigned short)wv3[4 + d]) * xv2;
      }
      qo[hh * 4 + sub * 2] = (short)f2bf(ql); qo[hh * 4 + sub * 2 + 1] = (short)f2bf(qh);
      ko[hh * 4 + sub * 2] = (short)f2bf(kl); ko[hh * 4 + sub * 2 + 1] = (short)f2bf(kh2);
      vo[hh * 4 + sub * 2] = (short)f2bf(vl); vo[hh * 4 + sub * 2 + 1] = (short)f2bf(vh);
    }
  *(short8v*)(q + (size_t)bs * INNERD + c0) = qo;
  *(short8v*)(k + (size_t)bs * INNERD + c0) = ko;
  *(short8v*)(v + (size_t)bs * INNERD + c0) = vo;
  float r8[8];
#pragma unroll
  for (int j = 0; j < 4; ++j) {
    const short8v ca = *(const short8v*)(CgT + (size_t)j * INNERD + c0);
    const short8v cm = *(const short8v*)(CgT + (size_t)(4 + j) * INNERD + c0);
    const short8v fa = *(const short8v*)(CgT + (size_t)(8 + j) * INNERD + c0);
    const short8v fm = *(const short8v*)(CgT + (size_t)(12 + j) * INNERD + c0);
    float si = 0.f, sf = 0.f;
#pragma unroll
    for (int u = 0; u < 8; ++u) {
      si += xa8[u] * bf2f((unsigned short)ca[u]) + xm8[u] * bf2f((unsigned short)cm[u]);
      sf += xa8[u] * bf2f((unsigned short)fa[u]) + xm8[u] * bf2f((unsigned short)fm[u]);
    }
    r8[j] = si; r8[4 + j] = sf;
  }
  const int l = t & 63;
  const bool b1 = (l & 1), b2 = (l & 2), b4 = (l & 4);
  float t4[4];
#pragma unroll
  for (int i = 0; i < 4; ++i) {
    const float send = b1 ? r8[i] : r8[i + 4];
    const float recv = __shfl_xor(send, 1, 64);
    t4[i] = (b1 ? r8[i + 4] : r8[i]) + recv;
  }
  float u2[2];
#pragma unroll
  for (int i = 0; i < 2; ++i) {
    const float send = b2 ? t4[i] : t4[i + 2];
    const float recv = __shfl_xor(send, 2, 64);
    u2[i] = (b2 ? t4[i + 2] : t4[i]) + recv;
  }
  float wsum;
  {
    const float send = b4 ? u2[0] : u2[1];
    const float recv = __shfl_xor(send, 4, 64);
    wsum = (b4 ? u2[1] : u2[0]) + recv;
  }
  wsum += __shfl_xor(wsum, 8, 64);
  wsum += __shfl_xor(wsum, 16, 64);
  wsum += __shfl_xor(wsum, 32, 64);
  if (l < 8) {
    const int perm = ((l & 1) << 2) | (l & 2) | ((l >> 2) & 1);
    red2[t >> 6][perm] = wsum;
  }
  __syncthreads();
  if (t < 8) {
    const float sum = red2[0][t] + red2[1][t] + red2[2][t] + red2[3][t];
    const int b = bs >> 11;
    if (t < 4) igpre[((size_t)(b * NHEAD + t)) * S_LEN + s] = sum + big[t];
    else fgpre[((size_t)(b * NHEAD + t - 4)) * S_LEN + s] = sum + bfg[t - 4];
  }
}

// -------- per-(b,n) scan --------
__global__ __launch_bounds__(256) void scan_kernel(const float* __restrict__ igpre,
                                                   const float* __restrict__ fgpre,
                                                   float* __restrict__ a_o,
                                                   float* __restrict__ rm_o,
                                                   float* __restrict__ e_o) {
  __shared__ float sd[256];
  const int bn = blockIdx.x, t = threadIdx.x;
  const size_t base = (size_t)bn * S_LEN + t * 8;
  float cs[8];
  float run = 0.0f;
#pragma unroll
  for (int u = 0; u < 8; ++u) { run += logsigf(fgpre[base + u]); cs[u] = run; }
  sd[t] = run;
  __syncthreads();
  for (int off = 1; off < 256; off <<= 1) {
    const float vv2 = (t >= off) ? sd[t - off] : 0.0f;
    __syncthreads();
    sd[t] += vv2;
    __syncthreads();
  }
  const float exs = (t > 0) ? sd[t - 1] : 0.0f;
  __syncthreads();
  float av[8], pm[8];
  float rmax = -INFINITY;
#pragma unroll
  for (int u = 0; u < 8; ++u) {
    const float L = exs + cs[u];
    cs[u] = L;
    av[u] = igpre[base + u] - L;
    rmax = fmaxf(rmax, av[u]);
    pm[u] = rmax;
  }
  sd[t] = rmax;
  __syncthreads();
  for (int off = 1; off < 256; off <<= 1) {
    const float vv2 = (t >= off) ? sd[t - off] : -INFINITY;
    __syncthreads();
    sd[t] = fmaxf(sd[t], vv2);
    __syncthreads();
  }
  const float exm = (t > 0) ? sd[t - 1] : -INFINITY;
#pragma unroll
  for (int u = 0; u < 8; ++u) {
    const float rmv = fmaxf(exm, pm[u]);
    a_o[base + u] = av[u];
    rm_o[base + u] = rmv;
    e_o[base + u] = expf(-(cs[u] + rmv));
  }
}

// ---------------- mLSTM core: MFMA flash-style, double-buffered K, counted vmcnt ----------
__global__ __launch_bounds__(512, 2) void mlstm_mfma(
    const unsigned short* __restrict__ qg, const unsigned short* __restrict__ kg,
    const unsigned short* __restrict__ vtg,
    const float* __restrict__ ag, const float* __restrict__ rmg,
    float* __restrict__ hraw, float* __restrict__ rsumg) {
  __shared__ unsigned short Ks[2][64 * 512];  // 2 x 64KB, rows 1KB, XOR (row&7)<<4
  __shared__ unsigned short Ps[64 * 64];      // 8KB, rows 128B, XOR (row&7)<<4
  __shared__ float rsl[8][16];
  const int tid = threadIdx.x;
  const int w = tid >> 6, l = tid & 63;
  const int lm = l & 15, l4 = l >> 4;
  const int beta = blockIdx.x;
  const int bn = beta & 7;          // XCD locality for vT/K panels
  const int part = (beta >> 3) & 1;
  const int idx = beta >> 4;
  const int qi = (idx < 16) ? (31 - idx) : (idx - 16);  // heavy blocks first
  const int i0 = qi << 6;
  const int b = bn >> 2, n = bn & 3;
  float* hp = hraw + (size_t)part * ((size_t)BATCH * S_LEN * INNERD);
  float* rp = rsumg + (size_t)part * ((size_t)BATCH * NHEAD * S_LEN);

  const int rA = ((w >> 1) << 4) + lm;
  short8v qf[16];
  {
    const unsigned short* qp = qg + (size_t)(b * S_LEN + i0 + rA) * INNERD + n * DHEAD + l4 * 8;
#pragma unroll
    for (int ks = 0; ks < 16; ++ks) qf[ks] = *(const short8v*)(qp + ks * 32);
  }
  const int rD = ((w >> 1) << 4) + (l4 << 2);
  float rm4[4];
#pragma unroll
  for (int r = 0; r < 4; ++r) rm4[r] = rmg[(size_t)bn * S_LEN + i0 + rD + r];
  const int cb0 = (w & 1) << 1;

  f32x4 acc[16];
#pragma unroll
  for (int i2 = 0; i2 < 16; ++i2) acc[i2] = (f32x4){0.f, 0.f, 0.f, 0.f};
  float rs4[4] = {0.f, 0.f, 0.f, 0.f};

  // tiles for this part: jt = part + 2*tau, tau in [0, ntau)
  const int ntau = (qi + 2 - part) >> 1;
  __builtin_amdgcn_sched_barrier(0);
  // prologue stage: tile 0 into Ks[0]  (8 gll16 per thread)
  if (ntau > 0) {
#pragma unroll
    for (int it = 0; it < 8; ++it) {
      const int row = it * 8 + w;
      gll16((const char*)kg + ((size_t)(b * S_LEN + part * 64 + row) * INNERD + n * DHEAD) * 2 + ((l * 16) ^ (w << 4)),
            (char*)Ks[0] + row * 1024);
    }
  }
  __builtin_amdgcn_sched_barrier(0);

  for (int tau = 0; tau < ntau; ++tau) {
    const int j0 = (part + 2 * tau) << 6;
    const int cur = tau & 1;
    // --- group A loads: vf (8 b128) + a0,a1 (2 dword) ---
    short8v vf[8];
#pragma unroll
    for (int db = 0; db < 4; ++db)
#pragma unroll
      for (int ks = 0; ks < 2; ++ks)
        vf[db * 2 + ks] = *(const short8v*)(vtg + (size_t)(bn * DHEAD + w * 64 + db * 16 + lm) * S_LEN + j0 + ks * 32 + l4 * 8);
    const float a0 = ag[(size_t)bn * S_LEN + j0 + cb0 * 16 + lm];
    const float a1 = ag[(size_t)bn * S_LEN + j0 + cb0 * 16 + 16 + lm];
    __builtin_amdgcn_sched_barrier(0);
    // --- stage next tile (8 gll16) ---
    const bool hasnext = (tau + 1 < ntau);
    if (hasnext) {
#pragma unroll
      for (int it = 0; it < 8; ++it) {
        const int row = it * 8 + w;
        gll16((const char*)kg + ((size_t)(b * S_LEN + j0 + 128 + row) * INNERD + n * DHEAD) * 2 + ((l * 16) ^ (w << 4)),
              (char*)Ks[cur ^ 1] + row * 1024);
      }
    }
    __builtin_amdgcn_sched_barrier(0);
    // wait: current stage done. queue = [stage_cur 8][vf+a 10][stage_next 0/8]
    if (hasnext) { asm volatile("s_waitcnt vmcnt(18)" ::: "memory"); }
    else         { asm volatile("s_waitcnt vmcnt(10)" ::: "memory"); }
    __builtin_amdgcn_sched_barrier(0);
    __builtin_amdgcn_s_barrier();
    // --- QK^T on Ks[cur] ---
    f32x4 s0 = (f32x4){0.f, 0.f, 0.f, 0.f}, s1 = (f32x4){0.f, 0.f, 0.f, 0.f};
    const char* kb0 = (const char*)Ks[cur] + (cb0 * 16 + lm) * 1024;
    const char* kb1 = (const char*)Ks[cur] + ((cb0 + 1) * 16 + lm) * 1024;
    __builtin_amdgcn_s_setprio(1);
#pragma unroll
    for (int ks = 0; ks < 16; ++ks) {
      const int off = (ks * 64 + l4 * 16) ^ ((lm & 7) << 4);
      const short8v b0 = *(const short8v*)(kb0 + off);
      const short8v b1 = *(const short8v*)(kb1 + off);
      s0 = MFMA_BF16(qf[ks], b0, s0);
      s1 = MFMA_BF16(qf[ks], b1, s1);
    }
    __builtin_amdgcn_s_setprio(0);
    // --- gate + causal mask + rowsum + P write ---
#pragma unroll
    for (int half = 0; half < 2; ++half) {
      const f32x4 sv = half ? s1 : s0;
      const float av = half ? a1 : a0;
      const int jl = (cb0 + half) * 16 + lm;
#pragma unroll
      for (int r = 0; r < 4; ++r) {
        const int il = rD + r;
        const float es = __expf(av - rm4[r]);
        const float p = (j0 + jl <= i0 + il) ? sv[r] * SCALE_QK * es : 0.0f;
        rs4[r] += p;
        *((unsigned short*)((char*)Ps + il * 128 + ((jl * 2) ^ ((il & 7) << 4)))) = f2bf(p);
      }
    }
    asm volatile("s_waitcnt lgkmcnt(0)" ::: "memory");
    __builtin_amdgcn_sched_barrier(0);
    __builtin_amdgcn_s_barrier();
    // --- PV ---
#pragma unroll
    for (int ks = 0; ks < 2; ++ks) {
      short8v pa[4];
#pragma unroll
      for (int rb = 0; rb < 4; ++rb)
        pa[rb] = *(const short8v*)((const char*)Ps + (rb * 16 + lm) * 128 + ((ks * 64 + l4 * 16) ^ ((lm & 7) << 4)));
      __builtin_amdgcn_s_setprio(1);
#pragma unroll
      for (int rb = 0; rb < 4; ++rb)
#pragma unroll
        for (int db = 0; db < 4; ++db)
          acc[rb * 4 + db] = MFMA_BF16(pa[rb], vf[db * 2 + ks], acc[rb * 4 + db]);
      __builtin_amdgcn_s_setprio(0);
    }
  }
  // rowsum combine via LDS (two waves share each 16-row block)
#pragma unroll
  for (int r = 0; r < 4; ++r) {
    float v2 = rs4[r];
    v2 += __shfl_xor(v2, 1, 64);
    v2 += __shfl_xor(v2, 2, 64);
    v2 += __shfl_xor(v2, 4, 64);
    v2 += __shfl_xor(v2, 8, 64);
    if (lm == 0) rsl[w][l4 * 4 + r] = v2;
  }
  asm volatile("s_waitcnt lgkmcnt(0)" ::: "memory");
  __builtin_amdgcn_s_barrier();
  if (tid < 64) {
    const int rblk = tid >> 4, rloc = tid & 15;
    rp[(size_t)bn * S_LEN + i0 + rblk * 16 + rloc] = rsl[rblk * 2][rloc] + rsl[rblk * 2 + 1][rloc];
  }
  // raw h partial store (zero when loop empty)
#pragma unroll
  for (int rb = 0; rb < 4; ++rb)
#pragma unroll
    for (int db = 0; db < 4; ++db) {
      float* dst = hp + (size_t)(b * S_LEN + i0 + rb * 16 + l4 * 4) * INNERD + n * DHEAD + w * 64 + db * 16 + lm;
#pragma unroll
      for (int r = 0; r < 4; ++r) dst[(size_t)r * INNERD] = acc[rb * 4 + db][r];
    }
}

// ------- mhln: merge partials + norm + LN + conv-skip + swish(z), bf16 out -------
__global__ __launch_bounds__(256) void mhln_kernel(
    const float* __restrict__ h, const unsigned short* __restrict__ xm,
    const unsigned short* __restrict__ zb,
    const float* __restrict__ cw, const float* __restrict__ cbias,
    const float* __restrict__ rsumg, const float* __restrict__ eg,
    const float* __restrict__ normw, const float* __restrict__ skip,
    unsigned short* __restrict__ hstate) {
  const int bs = blockIdx.x, t = threadIdx.x;
  const int bb = bs >> 11, s = bs & (S_LEN - 1);
  const int n = t >> 6, lane = t & 63;
  const int cp0 = n * DHEAD + lane * 8;
  const size_t hb = (size_t)bs * INNERD + cp0;
  const size_t HOFF = (size_t)BATCH * S_LEN * INNERD;
  const int bn = bb * NHEAD + n;
  const float rsv = rsumg[(size_t)bn * S_LEN + s] + rsumg[(size_t)BATCH * NHEAD * S_LEN + bn * S_LEN + s];
  const float ev = eg[(size_t)bn * S_LEN + s];
  const float inorm = 1.0f / (fmaxf(fabsf(rsv), ev) + 1e-6f);
  const float4 v0 = *(const float4*)(h + hb);
  const float4 v1 = *(const float4*)(h + hb + 4);
  const float4 u0 = *(const float4*)(h + HOFF + hb);
  const float4 u1 = *(const float4*)(h + HOFF + hb + 4);
  float vals[8] = {(v0.x + u0.x) * inorm, (v0.y + u0.y) * inorm, (v0.z + u0.z) * inorm,
                   (v0.w + u0.w) * inorm, (v1.x + u1.x) * inorm, (v1.y + u1.y) * inorm,
                   (v1.z + u1.z) * inorm, (v1.w + u1.w) * inorm};
  float sum = 0.0f;
#pragma unroll
  for (int u = 0; u < 8; ++u) sum += vals[u];
#pragma unroll
  for (int m = 32; m >= 1; m >>= 1) sum += __shfl_xor(sum, m, 64);
  const float mu = sum * (1.0f / 512.0f);
  float vs2 = 0.0f;
#pragma unroll
  for (int u = 0; u < 8; ++u) { const float d = vals[u] - mu; vs2 += d * d; }
#pragma unroll
  for (int m = 32; m >= 1; m >>= 1) vs2 += __shfl_xor(vs2, m, 64);
  const float rstd = rsqrtf(vs2 * (1.0f / 512.0f) + 1e-6f);
  float xa8[8];
  {
    float accv[8];
#pragma unroll
    for (int u = 0; u < 8; ++u) accv[u] = cbias[cp0 + u];
#pragma unroll
    for (int i2 = 0; i2 < 4; ++i2) {
      const int sj = s - 3 + i2;
      if (sj >= 0) {
        const short8v xv = *(const short8v*)(xm + (size_t)(bs - 3 + i2) * INNERD + cp0);
#pragma unroll
        for (int u = 0; u < 8; ++u)
          accv[u] += bf2f((unsigned short)xv[u]) * cw[i2 * INNERD + cp0 + u];
      }
    }
#pragma unroll
    for (int u = 0; u < 8; ++u) xa8[u] = swishf(accv[u]);
  }
  const short8v zv = *(const short8v*)(zb + (size_t)bs * INNERD + cp0);
  short8v o;
#pragma unroll
  for (int u = 0; u < 8; ++u) {
    const int cp = cp0 + u;
    const float hn = (vals[u] - mu) * rstd * normw[cp];
    const float z = bf2f((unsigned short)zv[u]);
    o[u] = (short)f2bf((hn + skip[cp] * xa8[u]) * swishf(z));
  }
  *(short8v*)(hstate + hb) = o;
}

extern "C" void kernel_launch(void* const* d_in, const int* in_sizes, int n_in,
                              void* d_out, int out_size, void* d_ws, size_t ws_size,
                              hipStream_t stream) {
  const float* x     = (const float*)d_in[0];
  const float* Wup   = (const float*)d_in[1];
  const float* cw    = (const float*)d_in[2];
  const float* cb    = (const float*)d_in[3];
  const float* Wq    = (const float*)d_in[4];
  const float* Wk    = (const float*)d_in[5];
  const float* Wv    = (const float*)d_in[6];
  const float* Wig   = (const float*)d_in[7];
  const float* big   = (const float*)d_in[8];
  const float* Wfg   = (const float*)d_in[9];
  const float* bfg   = (const float*)d_in[10];
  const float* normw = (const float*)d_in[11];
  const float* skip  = (const float*)d_in[12];
  const float* Wdown = (const float*)d_in[13];
  float* out = (float*)d_out;

  float* ws = (float*)d_ws;
  size_t off = 0;
  const size_t MR = (size_t)BATCH * S_LEN;  // 4096
  const size_t GSZ = (size_t)BATCH * NHEAD * S_LEN;  // 16384
  unsigned short* xm  = (unsigned short*)(ws + off); off += MR * INNERD / 2;
  unsigned short* zb  = (unsigned short*)(ws + off); off += MR * INNERD / 2;
  float* hraw         = ws + off;                    off += 2 * MR * INNERD;   // two partials
  unsigned short* qb  = (unsigned short*)(ws + off); off += MR * INNERD / 2;
  unsigned short* kb  = (unsigned short*)(ws + off); off += MR * INNERD / 2;
  unsigned short* vt  = (unsigned short*)(ws + off); off += MR * INNERD / 2;
  float* igpre  = ws + off; off += GSZ;
  float* fgpre  = ws + off; off += GSZ;
  float* a_buf  = ws + off; off += GSZ;
  float* rm_buf = ws + off; off += GSZ;
  float* e_buf  = ws + off; off += GSZ;
  float* rsum   = ws + off; off += 2 * GSZ;          // two partials
  unsigned short* Wpk = (unsigned short*)(ws + off); off += 12 * 256 * 8 / 2;
  unsigned short* CgT = (unsigned short*)(ws + off); off += 16 * (size_t)INNERD / 2;
  if (ws_size < off * sizeof(float)) return;

  // aliases into dead regions
  unsigned short* vb     = (unsigned short*)hraw;                       // dead before mlstm writes
  unsigned short* x_bf   = (unsigned short*)(hraw + MR * INNERD);       // part-1 region, dead before mlstm
  unsigned short* WupT   = vt;                                          // dead before trv writes vt
  unsigned short* WdT    = kb;                                          // dead after mlstm
  unsigned short* hstate = qb;                                          // dead after mlstm

  prep_kernel<<<1, 256, 0, stream>>>(Wq, Wk, Wv, Wig, Wfg, Wpk, CgT);
  cast_kernel<<<2048, 256, 0, stream>>>(x, x_bf);
  trc_kernel<<<dim3(32, 8), 256, 0, stream>>>(Wup, WupT, 1024, 4096);
  gemm_bf16<128, 1><<<dim3(32, 32), 256, 0, stream>>>(x_bf, WupT, nullptr, xm, zb, 4096, 4096, 1024);
  headwise_kernel<<<4096, 256, 0, stream>>>(xm, Wpk, CgT, cw, cb, big, bfg,
                                            qb, kb, vb, igpre, fgpre);
  trv_kernel<<<dim3(16, 4, 8), 256, 0, stream>>>(vb, vt);
  scan_kernel<<<8, 256, 0, stream>>>(igpre, fgpre, a_buf, rm_buf, e_buf);
  mlstm_mfma<<<512, 512, 0, stream>>>(qb, kb, vt, a_buf, rm_buf, hraw, rsum);
  trc_kernel<<<dim3(8, 16), 256, 0, stream>>>(Wdown, WdT, 2048, 1024);
  mhln_kernel<<<4096, 256, 0, stream>>>(hraw, xm, zb, cw, cb, rsum, e_buf, normw, skip, hstate);
  gemm_bf16<64, 0><<<dim3(16, 32), 256, 0, stream>>>(hstate, WdT, out, nullptr, nullptr, 4096, 1024, 2048);
}